// Round 3
// baseline (310.647 us; speedup 1.0000x reference)
//
#include <hip/hip_runtime.h>

#define B_ 2
#define T_ 2048
#define C_ 1024
#define H_ 16
#define DH_ 64

typedef __attribute__((ext_vector_type(8))) _Float16 half8;  // 8 f16 (4 VGPRs)
typedef __attribute__((ext_vector_type(4))) _Float16 half4;  // 4 f16 (2 VGPRs)
typedef __attribute__((ext_vector_type(2))) __fp16 fp16x2;   // cvt_pkrtz result type
typedef __attribute__((ext_vector_type(4))) float f32x4;
typedef __attribute__((ext_vector_type(16))) float f32x16;

__device__ __forceinline__ unsigned short f2h(float f) {
    union { _Float16 h; unsigned short u; } cv; cv.h = (_Float16)f; return cv.u;
}
__device__ __forceinline__ unsigned pk2(float a, float b) {
    union { fp16x2 h; unsigned u; } cv;
    cv.h = __builtin_amdgcn_cvt_pkrtz(a, b);
    return cv.u;
}
// swap lanes 32-63 of a with lanes 0-31 of b (gfx950)
__device__ __forceinline__ void plswap(unsigned &a, unsigned &b) {
    asm volatile("v_permlane32_swap_b32 %0, %1" : "+v"(a), "+v"(b));
}

__device__ __forceinline__ void gll16(const void* g, void* l) {
    __builtin_amdgcn_global_load_lds(
        (const __attribute__((address_space(1))) void*)g,
        (__attribute__((address_space(3))) void*)l, 16, 0, 0);
}

// ---------------------------------------------------------------------------
// Prep (single launch): blocks [0,2048): x fp32->fp16 (+mask vec in block 0,
// split-K flag zeroing in block 1); blocks [2048, 5120): W transpose+convert.
// ---------------------------------------------------------------------------
__global__ __launch_bounds__(256) void prep_kernel(
    const float* __restrict__ x, unsigned short* __restrict__ xf,
    const int* __restrict__ mask, unsigned short* __restrict__ mb,
    const float* __restrict__ Wq, const float* __restrict__ Wk,
    const float* __restrict__ Wv, unsigned short* __restrict__ wt,
    unsigned* __restrict__ flags)
{
    __shared__ float tile[32][33];
    const int tid = threadIdx.x;

    if (blockIdx.x < 2048) {
        const size_t idx8 = ((size_t)blockIdx.x * 256 + tid) * 8;
        float4 v0 = *(const float4*)(x + idx8);
        float4 v1 = *(const float4*)(x + idx8 + 4);
        float f[8] = {v0.x, v0.y, v0.z, v0.w, v1.x, v1.y, v1.z, v1.w};
        unsigned short h[8];
#pragma unroll
        for (int i = 0; i < 8; i++) h[i] = f2h(f[i]);
        *(uint4*)(xf + idx8) = *(const uint4*)h;

        if (blockIdx.x == 0) {
#pragma unroll
            for (int j = 0; j < 16; j++) {
                int i = tid * 16 + j;               // covers B_*T_ = 4096
                mb[i] = (mask[i] != 0) ? (unsigned short)0x3C00 : (unsigned short)0;
            }
        }
        if (blockIdx.x == 1) {                      // zero split-K flags (512)
            flags[tid] = 0u;
            flags[tid + 256] = 0u;
        }
    } else {
        const int idx = blockIdx.x - 2048;
        const int z   = idx >> 10;
        const int rem = idx & 1023;
        const int n0  = (rem & 31) * 32;
        const int k0  = (rem >> 5) * 32;
        const float* __restrict__ W = (z == 0) ? Wq : (z == 1) ? Wk : Wv;
        unsigned short* __restrict__ wtz = wt + (size_t)z * C_ * C_;
        const int tx = tid & 31;
        const int ty = tid >> 5;                    // 0..7
#pragma unroll
        for (int j = 0; j < 4; j++)
            tile[ty + j * 8][tx] = W[(size_t)(k0 + ty + j * 8) * C_ + n0 + tx];
        __syncthreads();
#pragma unroll
        for (int j = 0; j < 4; j++)
            wtz[(size_t)(n0 + ty + j * 8) * C_ + k0 + tx] = f2h(tile[tx][ty + j * 8]);
    }
}

// ---------------------------------------------------------------------------
// QKV projection (R12 structure — best measured). z-grid, 768 blocks = 3/CU,
// 32 KB LDS. Q pre-scaled by log2(e)/8; V transposed + mask-zeroed.
// ---------------------------------------------------------------------------
__global__ __launch_bounds__(256) void qkv_mfma_kernel(
    const unsigned short* __restrict__ xf, const unsigned short* __restrict__ wt,
    const float* __restrict__ bq, const float* __restrict__ bk,
    const float* __restrict__ bv, const int* __restrict__ maskp,
    unsigned short* __restrict__ qb, unsigned short* __restrict__ kb,
    unsigned short* __restrict__ vt)
{
    __shared__ unsigned short sX[128 * 64];
    __shared__ unsigned short sW[128 * 64];

    const int z = blockIdx.z;
    const float* __restrict__ bias = (z == 0) ? bq : (z == 1) ? bk : bv;
    const unsigned short* __restrict__ wtz = wt + (size_t)z * C_ * C_;

    const int tok0 = blockIdx.x * 128;
    const int col0 = blockIdx.y * 128;
    const int wv    = threadIdx.x >> 6;
    const int lane  = threadIdx.x & 63;
    const int l15   = lane & 15;
    const int quad  = lane >> 4;
    const int l7    = l15 & 7;
    const int wm    = wv >> 1;
    const int wn    = wv & 1;
    const int lrow8 = lane >> 3;
    const int gch   = (lane & 7) ^ lrow8;

    f32x4 acc[4][4];
#pragma unroll
    for (int i = 0; i < 4; i++)
#pragma unroll
        for (int j = 0; j < 4; j++) acc[i][j] = (f32x4){0.f, 0.f, 0.f, 0.f};

    int aoff[4][2], boff[4][2];
#pragma unroll
    for (int i = 0; i < 4; i++)
#pragma unroll
        for (int s = 0; s < 2; s++) {
            aoff[i][s] = (wm * 64 + i * 16 + l15) * 64 + (((s * 4 + quad) ^ l7) * 8);
            boff[i][s] = (wn * 64 + i * 16 + l15) * 64 + (((s * 4 + quad) ^ l7) * 8);
        }

    const unsigned short* Abuf = (z < 2) ? sX : sW;
    const unsigned short* Bbuf = (z < 2) ? sW : sX;

    for (int k0 = 0; k0 < C_; k0 += 64) {
        __syncthreads();
#pragma unroll
        for (int s = 0; s < 8; ++s) {
            int g    = (s << 2) + wv;
            int tsel = g >> 4;
            int r0   = (g & 15) << 3;
            const unsigned short* src = tsel ? wtz : xf;
            unsigned short*       dst = tsel ? sW  : sX;
            int rowg = tsel ? col0 : tok0;
            gll16(src + (size_t)(rowg + r0 + lrow8) * C_ + k0 + gch * 8,
                  dst + r0 * 64);
        }
        __syncthreads();

        half8 af[4][2], bf_[4][2];
#pragma unroll
        for (int i = 0; i < 4; i++)
#pragma unroll
            for (int s = 0; s < 2; s++) {
                af[i][s]  = *(const half8*)&Abuf[aoff[i][s]];
                bf_[i][s] = *(const half8*)&Bbuf[boff[i][s]];
            }
#pragma unroll
        for (int s = 0; s < 2; s++)
#pragma unroll
            for (int j = 0; j < 4; j++)
#pragma unroll
                for (int i = 0; i < 4; i++)
                    acc[i][j] = __builtin_amdgcn_mfma_f32_16x16x32_f16(
                        af[i][s], bf_[j][s], acc[i][j], 0, 0, 0);
    }

    if (z == 0) {
#pragma unroll
        for (int j = 0; j < 4; j++) {
            int col = col0 + wn * 64 + j * 16 + l15;
            int h = col >> 6, d = col & 63;
            float bs = bias[col];
#pragma unroll
            for (int i = 0; i < 4; i++) {
#pragma unroll
                for (int r = 0; r < 4; r++) {
                    int tok = tok0 + wm * 64 + i * 16 + quad * 4 + r;
                    int bidx = tok >> 11, t = tok & (T_ - 1);
                    qb[((size_t)(bidx * H_ + h) * T_ + t) * DH_ + d] =
                        f2h((acc[i][j][r] + bs) * 0.18033688011112042f);
                }
            }
        }
    } else if (z == 1) {
#pragma unroll
        for (int j = 0; j < 4; j++) {
            int col = col0 + wn * 64 + j * 16 + l15;
            int h = col >> 6, d = col & 63;
            float bs = bias[col];
#pragma unroll
            for (int i = 0; i < 4; i++) {
#pragma unroll
                for (int r = 0; r < 4; r++) {
                    int tok = tok0 + wm * 64 + i * 16 + quad * 4 + r;
                    int bidx = tok >> 11, t = tok & (T_ - 1);
                    kb[((size_t)(bidx * H_ + h) * T_ + t) * DH_ + d] =
                        f2h(acc[i][j][r] + bs);
                }
            }
        }
    } else {
        float mv4[4]; int bidx4[4], t4[4];
#pragma unroll
        for (int j = 0; j < 4; j++) {
            int tok = tok0 + wn * 64 + j * 16 + l15;
            bidx4[j] = tok >> 11; t4[j] = tok & (T_ - 1);
            mv4[j] = (maskp[bidx4[j] * T_ + t4[j]] != 0) ? 1.f : 0.f;
        }
#pragma unroll
        for (int i = 0; i < 4; i++) {
#pragma unroll
            for (int r = 0; r < 4; r++) {
                int col = col0 + wm * 64 + i * 16 + quad * 4 + r;
                int h = col >> 6, d = col & 63;
                float bs = bias[col];
#pragma unroll
                for (int j = 0; j < 4; j++) {
                    vt[((size_t)(bidx4[j] * H_ + h) * DH_ + d) * T_ + t4[j]] =
                        f2h((acc[i][j][r] + bs) * mv4[j]);
                }
            }
        }
    }
}

// ---------------------------------------------------------------------------
// Attention R19: split-K=2 on the R18 32x32x16 structure. Grid (32,16,2);
// block z=ks handles keys [ks*1024, ks*1024+1024) over 16 kt tiles.
// Pipe work per CU unchanged; waves/CU 8 -> 16 (R2 showed latency-bound:
// max-pipe ~20-27us vs 53us measured, occupancy 17.6%).
// Order-free combine (no 4th launch, no dispatch-order assumption): first
// finisher of each (bh,qy) pair publishes unnormalized O into out + l into
// lo[] (release); second finisher acquire-spins (bounded: winner already
// resident), adds its partial, normalizes by combined l, writes final.
// ---------------------------------------------------------------------------
__global__ __launch_bounds__(256, 2) void attn_mfma_kernel(
    const unsigned short* __restrict__ qb,  // [32][2048][64] f16 (pre-scaled)
    const unsigned short* __restrict__ kb,  // [32][2048][64] f16
    const unsigned short* __restrict__ vt,  // [32][64][2048] f16 (mask-zeroed)
    const int* __restrict__ mask,           // [2][2048]
    const unsigned short* __restrict__ mb,  // [2][2048] f16 {0,1}
    float* __restrict__ out,                // [2][2048][1024]
    float* __restrict__ lo,                 // [32][2048] partial l (winner's)
    unsigned* __restrict__ flags)           // [512] zeroed by prep
{
    __shared__ unsigned short Ks[2][64 * 64];
    __shared__ unsigned short Vs[2][64 * 64];
    __shared__ unsigned role_sh;

    const int bh   = blockIdx.x;            // bh-major: same head -> same XCD
    const int b    = bh >> 4;
    const int h    = bh & 15;
    const int ks   = blockIdx.z;
    const int kb0  = ks << 10;              // key offset: 0 or 1024
    const int wv   = threadIdx.x >> 6;      // 0..3
    const int lane = threadIdx.x & 63;
    const int l31  = lane & 31;
    const int hi   = lane >> 5;
    const int l7b  = l31 & 7;               // row&7 for swizzled frag reads
    const int q0w  = blockIdx.y * 128 + wv * 32;

    const unsigned short* kbh = kb + (size_t)bh * T_ * DH_;
    const unsigned short* vbh = vt + (size_t)bh * DH_ * T_;
    const unsigned short* mbb = mb + b * T_;
    const int* __restrict__ mrow = mask + b * T_;

    // Q B-frags (32x32x16): B[k=dh][n=q]: lane n=l31, k = hi*8+j per m-chunk
    half8 qf[4];
#pragma unroll
    for (int m = 0; m < 4; ++m)
        qf[m] = *(const half8*)(qb + ((size_t)bh * T_ + q0w + l31) * DH_
                                + m * 16 + hi * 8);

    f32x16 o0, o1, lacc;
#pragma unroll
    for (int r = 0; r < 16; ++r) { o0[r] = 0.f; o1[r] = 0.f; lacc[r] = 0.f; }

    const int lrow = lane >> 3;
    const int gch  = (lane & 7) ^ lrow;

#pragma unroll
    for (int s = 0; s < 4; ++s) {
        int j  = (wv << 2) + s;
        int rb = j & 7;
        if (j < 8) gll16(kbh + (size_t)(kb0 + rb * 8 + lrow) * DH_ + gch * 8,
                         &Ks[0][rb * 512]);
        else       gll16(vbh + (size_t)(rb * 8 + lrow) * T_ + kb0 + gch * 8,
                         &Vs[0][rb * 512]);
    }

    for (int ktl = 0; ktl < 16; ++ktl) {
        const int cur   = ktl & 1;
        const int kbase = kb0 + ktl * 64;
        __syncthreads();

        if (ktl < 15) {
            const int nb = kbase + 64;
#pragma unroll
            for (int s = 0; s < 4; ++s) {
                int j  = (wv << 2) + s;
                int rb = j & 7;
                if (j < 8) gll16(kbh + (size_t)(nb + rb * 8 + lrow) * DH_ + gch * 8,
                                 &Ks[cur ^ 1][rb * 512]);
                else       gll16(vbh + (size_t)(rb * 8 + lrow) * T_ + nb + gch * 8,
                                 &Vs[cur ^ 1][rb * 512]);
            }
        }

        const unsigned short* Kc = &Ks[cur][0];
        const unsigned short* Vc = &Vs[cur][0];

        // mask B-frags for l-sum: every column n holds m[k]; k = chunk*16+hi*8+j
        half8 bm[4];
#pragma unroll
        for (int c = 0; c < 4; ++c)
            bm[c] = *(const half8*)(mbb + kbase + c * 16 + hi * 8);

        // S^T = K . Q^T per 32-key tile; exp2; pack to A-frags in registers.
        half8 pa[4];
#pragma unroll
        for (int st = 0; st < 2; ++st) {
            f32x16 sa;
#pragma unroll
            for (int r = 0; r < 16; ++r) sa[r] = 0.f;
#pragma unroll
            for (int m = 0; m < 4; ++m) {
                half8 kf = *(const half8*)(Kc + (st * 32 + l31) * 64
                                           + (((m * 2 + hi) ^ l7b) * 8));
                sa = __builtin_amdgcn_mfma_f32_32x32x16_f16(kf, qf[m], sa, 0, 0, 0);
            }
            float p[16];
#pragma unroll
            for (int r = 0; r < 16; ++r) p[r] = __builtin_amdgcn_exp2f(sa[r]);
            // C-layout k of reg r (rel. 16-key chunk): (r&3) + 8*(r>>2) + 4*hi.
            // A-frag word w = keys (hi*8+2w, hi*8+2w+1):
            //   swap(pk(p0,p1), pk(p4,p5)) -> w0, w2 ; swap(pk(p2,p3), pk(p6,p7)) -> w1, w3
#pragma unroll
            for (int kh = 0; kh < 2; ++kh) {
                unsigned w0 = pk2(p[kh * 8 + 0], p[kh * 8 + 1]);
                unsigned w2 = pk2(p[kh * 8 + 4], p[kh * 8 + 5]);
                unsigned w1 = pk2(p[kh * 8 + 2], p[kh * 8 + 3]);
                unsigned w3 = pk2(p[kh * 8 + 6], p[kh * 8 + 7]);
                plswap(w0, w2);
                plswap(w1, w3);
                union { unsigned u[4]; half8 hh; } cv;
                cv.u[0] = w0; cv.u[1] = w1; cv.u[2] = w2; cv.u[3] = w3;
                pa[st * 2 + kh] = cv.hh;
            }
        }

        // l += P . maskcol (all 32 output cols identical = l[q-row])
#pragma unroll
        for (int c = 0; c < 4; ++c)
            lacc = __builtin_amdgcn_mfma_f32_32x32x16_f16(pa[c], bm[c], lacc, 0, 0, 0);

        // O += P V  (V B-frags: n = d = l31 (+32), k = keys c*16+hi*8+j)
#pragma unroll
        for (int c = 0; c < 4; ++c) {
            half8 v0 = *(const half8*)(Vc + (l31) * 64      + (((c * 2 + hi) ^ l7b) * 8));
            half8 v1 = *(const half8*)(Vc + (32 + l31) * 64 + (((c * 2 + hi) ^ l7b) * 8));
            o0 = __builtin_amdgcn_mfma_f32_32x32x16_f16(pa[c], v0, o0, 0, 0, 0);
            o1 = __builtin_amdgcn_mfma_f32_32x32x16_f16(pa[c], v1, o1, 0, 0, 0);
        }
    }

    // ---- split-K combine (order-free) ----
    const int pidx = bh * 16 + blockIdx.y;
    if (threadIdx.x == 0)
        role_sh = __hip_atomic_fetch_add(&flags[pidx], 1u, __ATOMIC_ACQ_REL,
                                         __HIP_MEMORY_SCOPE_AGENT);
    __syncthreads();
    const unsigned role = role_sh;

    if (role == 0) {
        // winner: publish unnormalized partial O + partial l
#pragma unroll
        for (int r = 0; r < 16; ++r) {
            int q = q0w + (r & 3) + 8 * (r >> 2) + 4 * hi;
            float* orow = out + ((size_t)(b * T_ + q)) * C_ + h * DH_;
            orow[l31]      = o0[r];
            orow[32 + l31] = o1[r];
            if (l31 == 0) lo[bh * T_ + q] = lacc[r];
        }
        __threadfence();
        __syncthreads();
        if (threadIdx.x == 0)
            __hip_atomic_fetch_add(&flags[pidx], 4u, __ATOMIC_RELEASE,
                                   __HIP_MEMORY_SCOPE_AGENT);
    } else {
        // loser: wait for winner's publish (bounded spin: winner already
        // resident — it performed its atomic before ours)
        if (threadIdx.x == 0) {
            while (!(__hip_atomic_load(&flags[pidx], __ATOMIC_ACQUIRE,
                                       __HIP_MEMORY_SCOPE_AGENT) & 4u))
                __builtin_amdgcn_s_sleep(2);
        }
        __syncthreads();
        __threadfence();
#pragma unroll
        for (int r = 0; r < 16; ++r) {
            int q = q0w + (r & 3) + 8 * (r >> 2) + 4 * hi;
            float lsum = lacc[r] + lo[bh * T_ + q];
            float iv = (mrow[q] != 0 && lsum > 0.f) ? (1.0f / lsum) : 0.f;
            float* orow = out + ((size_t)(b * T_ + q)) * C_ + h * DH_;
            orow[l31]      = (o0[r] + orow[l31])      * iv;
            orow[32 + l31] = (o1[r] + orow[32 + l31]) * iv;
        }
    }
}

// ---------------------------------------------------------------------------
extern "C" void kernel_launch(void* const* d_in, const int* in_sizes, int n_in,
                              void* d_out, int out_size, void* d_ws, size_t ws_size,
                              hipStream_t stream)
{
    (void)in_sizes; (void)n_in; (void)out_size; (void)ws_size;
    const float* x  = (const float*)d_in[0];
    const float* Wq = (const float*)d_in[1];
    const float* bq = (const float*)d_in[2];
    const float* Wk = (const float*)d_in[3];
    const float* bk = (const float*)d_in[4];
    const float* Wv = (const float*)d_in[5];
    const float* bv = (const float*)d_in[6];
    const int* mask = (const int*)d_in[7];
    float* out = (float*)d_out;

    const size_t NX = (size_t)B_ * T_ * C_;          // 4 Mi elements
    unsigned short* xf = (unsigned short*)d_ws;       // 8 MB fp16 x
    unsigned short* wt = xf + NX;                     // 6 MB fp16 W^T x3
    unsigned short* qb = wt + (size_t)3 * C_ * C_;    // 8 MB (pre-scaled q)
    unsigned short* kb = qb + NX;                     // 8 MB
    unsigned short* vt = kb + NX;                     // 8 MB
    unsigned short* mb = vt + NX;                     // 8 KB (4096 f16)
    float* lo          = (float*)(mb + 4096);         // 256 KB partial l
    unsigned* flags    = (unsigned*)(lo + 32 * T_);   // 2 KB

    prep_kernel<<<5120, 256, 0, stream>>>(x, xf, mask, mb, Wq, Wk, Wv, wt, flags);
    qkv_mfma_kernel<<<dim3(32, 8, 3), 256, 0, stream>>>(
        xf, wt, bq, bk, bv, mask, qb, kb, vt);
    attn_mfma_kernel<<<dim3(32, 16, 2), 256, 0, stream>>>(
        qb, kb, vt, mask, mb, out, lo, flags);
}

// Round 4
// 195.158 us; speedup vs baseline: 1.5918x; 1.5918x over previous
//
#include <hip/hip_runtime.h>

#define B_ 2
#define T_ 2048
#define C_ 1024
#define H_ 16
#define DH_ 64

typedef __attribute__((ext_vector_type(8))) _Float16 half8;  // 8 f16 (4 VGPRs)
typedef __attribute__((ext_vector_type(4))) _Float16 half4;  // 4 f16 (2 VGPRs)
typedef __attribute__((ext_vector_type(2))) __fp16 fp16x2;   // cvt_pkrtz result type
typedef __attribute__((ext_vector_type(4))) float f32x4;
typedef __attribute__((ext_vector_type(16))) float f32x16;

__device__ __forceinline__ unsigned short f2h(float f) {
    union { _Float16 h; unsigned short u; } cv; cv.h = (_Float16)f; return cv.u;
}
__device__ __forceinline__ unsigned pk2(float a, float b) {
    union { fp16x2 h; unsigned u; } cv;
    cv.h = __builtin_amdgcn_cvt_pkrtz(a, b);
    return cv.u;
}
// swap lanes 32-63 of a with lanes 0-31 of b (gfx950)
__device__ __forceinline__ void plswap(unsigned &a, unsigned &b) {
    asm volatile("v_permlane32_swap_b32 %0, %1" : "+v"(a), "+v"(b));
}

__device__ __forceinline__ void gll16(const void* g, void* l) {
    __builtin_amdgcn_global_load_lds(
        (const __attribute__((address_space(1))) void*)g,
        (__attribute__((address_space(3))) void*)l, 16, 0, 0);
}

// ---------------------------------------------------------------------------
// Prep (single launch): blocks [0,2048): x fp32->fp16 (+mask vec in block 0);
// blocks [2048, 5120): W transpose+convert -> Wt[z] (fp16 [N][K]).
// ---------------------------------------------------------------------------
__global__ __launch_bounds__(256) void prep_kernel(
    const float* __restrict__ x, unsigned short* __restrict__ xf,
    const int* __restrict__ mask, unsigned short* __restrict__ mb,
    const float* __restrict__ Wq, const float* __restrict__ Wk,
    const float* __restrict__ Wv, unsigned short* __restrict__ wt)
{
    __shared__ float tile[32][33];
    const int tid = threadIdx.x;

    if (blockIdx.x < 2048) {
        const size_t idx8 = ((size_t)blockIdx.x * 256 + tid) * 8;
        float4 v0 = *(const float4*)(x + idx8);
        float4 v1 = *(const float4*)(x + idx8 + 4);
        float f[8] = {v0.x, v0.y, v0.z, v0.w, v1.x, v1.y, v1.z, v1.w};
        unsigned short h[8];
#pragma unroll
        for (int i = 0; i < 8; i++) h[i] = f2h(f[i]);
        *(uint4*)(xf + idx8) = *(const uint4*)h;

        if (blockIdx.x == 0) {
#pragma unroll
            for (int j = 0; j < 16; j++) {
                int i = tid * 16 + j;               // covers B_*T_ = 4096
                mb[i] = (mask[i] != 0) ? (unsigned short)0x3C00 : (unsigned short)0;
            }
        }
    } else {
        const int idx = blockIdx.x - 2048;
        const int z   = idx >> 10;
        const int rem = idx & 1023;
        const int n0  = (rem & 31) * 32;
        const int k0  = (rem >> 5) * 32;
        const float* __restrict__ W = (z == 0) ? Wq : (z == 1) ? Wk : Wv;
        unsigned short* __restrict__ wtz = wt + (size_t)z * C_ * C_;
        const int tx = tid & 31;
        const int ty = tid >> 5;                    // 0..7
#pragma unroll
        for (int j = 0; j < 4; j++)
            tile[ty + j * 8][tx] = W[(size_t)(k0 + ty + j * 8) * C_ + n0 + tx];
        __syncthreads();
#pragma unroll
        for (int j = 0; j < 4; j++)
            wtz[(size_t)(n0 + ty + j * 8) * C_ + k0 + tx] = f2h(tile[tx][ty + j * 8]);
    }
}

// ---------------------------------------------------------------------------
// QKV projection (R12 structure — best measured). z-grid, 768 blocks = 3/CU,
// 32 KB LDS. Q pre-scaled by log2(e)/8; V transposed + mask-zeroed.
// ---------------------------------------------------------------------------
__global__ __launch_bounds__(256) void qkv_mfma_kernel(
    const unsigned short* __restrict__ xf, const unsigned short* __restrict__ wt,
    const float* __restrict__ bq, const float* __restrict__ bk,
    const float* __restrict__ bv, const int* __restrict__ maskp,
    unsigned short* __restrict__ qb, unsigned short* __restrict__ kb,
    unsigned short* __restrict__ vt)
{
    __shared__ unsigned short sX[128 * 64];
    __shared__ unsigned short sW[128 * 64];

    const int z = blockIdx.z;
    const float* __restrict__ bias = (z == 0) ? bq : (z == 1) ? bk : bv;
    const unsigned short* __restrict__ wtz = wt + (size_t)z * C_ * C_;

    const int tok0 = blockIdx.x * 128;
    const int col0 = blockIdx.y * 128;
    const int wv    = threadIdx.x >> 6;
    const int lane  = threadIdx.x & 63;
    const int l15   = lane & 15;
    const int quad  = lane >> 4;
    const int l7    = l15 & 7;
    const int wm    = wv >> 1;
    const int wn    = wv & 1;
    const int lrow8 = lane >> 3;
    const int gch   = (lane & 7) ^ lrow8;

    f32x4 acc[4][4];
#pragma unroll
    for (int i = 0; i < 4; i++)
#pragma unroll
        for (int j = 0; j < 4; j++) acc[i][j] = (f32x4){0.f, 0.f, 0.f, 0.f};

    int aoff[4][2], boff[4][2];
#pragma unroll
    for (int i = 0; i < 4; i++)
#pragma unroll
        for (int s = 0; s < 2; s++) {
            aoff[i][s] = (wm * 64 + i * 16 + l15) * 64 + (((s * 4 + quad) ^ l7) * 8);
            boff[i][s] = (wn * 64 + i * 16 + l15) * 64 + (((s * 4 + quad) ^ l7) * 8);
        }

    const unsigned short* Abuf = (z < 2) ? sX : sW;
    const unsigned short* Bbuf = (z < 2) ? sW : sX;

    for (int k0 = 0; k0 < C_; k0 += 64) {
        __syncthreads();
#pragma unroll
        for (int s = 0; s < 8; ++s) {
            int g    = (s << 2) + wv;
            int tsel = g >> 4;
            int r0   = (g & 15) << 3;
            const unsigned short* src = tsel ? wtz : xf;
            unsigned short*       dst = tsel ? sW  : sX;
            int rowg = tsel ? col0 : tok0;
            gll16(src + (size_t)(rowg + r0 + lrow8) * C_ + k0 + gch * 8,
                  dst + r0 * 64);
        }
        __syncthreads();

        half8 af[4][2], bf_[4][2];
#pragma unroll
        for (int i = 0; i < 4; i++)
#pragma unroll
            for (int s = 0; s < 2; s++) {
                af[i][s]  = *(const half8*)&Abuf[aoff[i][s]];
                bf_[i][s] = *(const half8*)&Bbuf[boff[i][s]];
            }
#pragma unroll
        for (int s = 0; s < 2; s++)
#pragma unroll
            for (int j = 0; j < 4; j++)
#pragma unroll
                for (int i = 0; i < 4; i++)
                    acc[i][j] = __builtin_amdgcn_mfma_f32_16x16x32_f16(
                        af[i][s], bf_[j][s], acc[i][j], 0, 0, 0);
    }

    if (z == 0) {
#pragma unroll
        for (int j = 0; j < 4; j++) {
            int col = col0 + wn * 64 + j * 16 + l15;
            int h = col >> 6, d = col & 63;
            float bs = bias[col];
#pragma unroll
            for (int i = 0; i < 4; i++) {
#pragma unroll
                for (int r = 0; r < 4; r++) {
                    int tok = tok0 + wm * 64 + i * 16 + quad * 4 + r;
                    int bidx = tok >> 11, t = tok & (T_ - 1);
                    qb[((size_t)(bidx * H_ + h) * T_ + t) * DH_ + d] =
                        f2h((acc[i][j][r] + bs) * 0.18033688011112042f);
                }
            }
        }
    } else if (z == 1) {
#pragma unroll
        for (int j = 0; j < 4; j++) {
            int col = col0 + wn * 64 + j * 16 + l15;
            int h = col >> 6, d = col & 63;
            float bs = bias[col];
#pragma unroll
            for (int i = 0; i < 4; i++) {
#pragma unroll
                for (int r = 0; r < 4; r++) {
                    int tok = tok0 + wm * 64 + i * 16 + quad * 4 + r;
                    int bidx = tok >> 11, t = tok & (T_ - 1);
                    kb[((size_t)(bidx * H_ + h) * T_ + t) * DH_ + d] =
                        f2h(acc[i][j][r] + bs);
                }
            }
        }
    } else {
        float mv4[4]; int bidx4[4], t4[4];
#pragma unroll
        for (int j = 0; j < 4; j++) {
            int tok = tok0 + wn * 64 + j * 16 + l15;
            bidx4[j] = tok >> 11; t4[j] = tok & (T_ - 1);
            mv4[j] = (maskp[bidx4[j] * T_ + t4[j]] != 0) ? 1.f : 0.f;
        }
#pragma unroll
        for (int i = 0; i < 4; i++) {
#pragma unroll
            for (int r = 0; r < 4; r++) {
                int col = col0 + wm * 64 + i * 16 + quad * 4 + r;
                int h = col >> 6, d = col & 63;
                float bs = bias[col];
#pragma unroll
                for (int j = 0; j < 4; j++) {
                    vt[((size_t)(bidx4[j] * H_ + h) * DH_ + d) * T_ + t4[j]] =
                        f2h((acc[i][j][r] + bs) * mv4[j]);
                }
            }
        }
    }
}

// ---------------------------------------------------------------------------
// Attention R20: R18 structure (32x32x16, 4 waves x 32 q, grid 32x16 — split-K
// reverted: R3 proved the cross-XCD combine costs 4x more than the latency it
// hides). Change vs R18: V is read directly from global (L2-resident, 64x
// reuse, wave-uniform addresses -> L1 broadcast across the 4 waves) instead of
// being staged through LDS. This halves the LDS-read burst (16 -> 8 b128 per
// wave-kt), halves gll16 staging + barrier-drain payload, and removes the V
// share of bank conflicts. K stays in LDS (QK critical path needs on-chip BW).
// ---------------------------------------------------------------------------
__global__ __launch_bounds__(256, 2) void attn_mfma_kernel(
    const unsigned short* __restrict__ qb,  // [32][2048][64] f16 (pre-scaled)
    const unsigned short* __restrict__ kb,  // [32][2048][64] f16
    const unsigned short* __restrict__ vt,  // [32][64][2048] f16 (mask-zeroed)
    const int* __restrict__ mask,           // [2][2048]
    const unsigned short* __restrict__ mb,  // [2][2048] f16 {0,1}
    float* __restrict__ out)                // [2][2048][1024]
{
    __shared__ unsigned short Ks[2][64 * 64];

    const int bh   = blockIdx.x;            // bh-major: same head -> same XCD
    const int b    = bh >> 4;
    const int h    = bh & 15;
    const int wv   = threadIdx.x >> 6;      // 0..3
    const int lane = threadIdx.x & 63;
    const int l31  = lane & 31;
    const int hi   = lane >> 5;
    const int l7b  = l31 & 7;               // row&7 for swizzled frag reads
    const int q0w  = blockIdx.y * 128 + wv * 32;

    const unsigned short* kbh = kb + (size_t)bh * T_ * DH_;
    const unsigned short* vbh = vt + (size_t)bh * DH_ * T_;
    const unsigned short* mbb = mb + b * T_;
    const int* __restrict__ mrow = mask + b * T_;

    // Q B-frags (32x32x16): B[k=dh][n=q]: lane n=l31, k = hi*8+j per m-chunk
    half8 qf[4];
#pragma unroll
    for (int m = 0; m < 4; ++m)
        qf[m] = *(const half8*)(qb + ((size_t)bh * T_ + q0w + l31) * DH_
                                + m * 16 + hi * 8);

    f32x16 o0, o1, lacc;
#pragma unroll
    for (int r = 0; r < 16; ++r) { o0[r] = 0.f; o1[r] = 0.f; lacc[r] = 0.f; }

    const int lrow = lane >> 3;
    const int gch  = (lane & 7) ^ lrow;

    // prologue: stage K tile 0 (2 gll16 per wave)
#pragma unroll
    for (int s = 0; s < 2; ++s) {
        int rb = (wv << 1) + s;
        gll16(kbh + (size_t)(rb * 8 + lrow) * DH_ + gch * 8, &Ks[0][rb * 512]);
    }

    for (int kt = 0; kt < 32; ++kt) {
        const int cur   = kt & 1;
        const int kbase = kt * 64;
        __syncthreads();

        if (kt < 31) {
            const int nb = kbase + 64;
#pragma unroll
            for (int s = 0; s < 2; ++s) {
                int rb = (wv << 1) + s;
                gll16(kbh + (size_t)(nb + rb * 8 + lrow) * DH_ + gch * 8,
                      &Ks[cur ^ 1][rb * 512]);
            }
        }

        const unsigned short* Kc = &Ks[cur][0];

        // V B-frags straight from global (L2): B[k=key][n=d]. Issue early —
        // independent of the QK chain; compiler counts vmcnt to the PV use.
        half8 vfr[2][4];
#pragma unroll
        for (int c = 0; c < 4; ++c) {
            vfr[0][c] = *(const half8*)(vbh + (size_t)l31 * T_
                                        + kbase + c * 16 + hi * 8);
            vfr[1][c] = *(const half8*)(vbh + (size_t)(32 + l31) * T_
                                        + kbase + c * 16 + hi * 8);
        }

        // mask B-frags for l-sum: every column n holds m[k]; k = chunk*16+hi*8+j
        half8 bm[4];
#pragma unroll
        for (int c = 0; c < 4; ++c)
            bm[c] = *(const half8*)(mbb + kbase + c * 16 + hi * 8);

        // S^T = K . Q^T per 32-key tile; exp2; pack to A-frags in registers.
        half8 pa[4];
#pragma unroll
        for (int st = 0; st < 2; ++st) {
            f32x16 sa;
#pragma unroll
            for (int r = 0; r < 16; ++r) sa[r] = 0.f;
#pragma unroll
            for (int m = 0; m < 4; ++m) {
                half8 kf = *(const half8*)(Kc + (st * 32 + l31) * 64
                                           + (((m * 2 + hi) ^ l7b) * 8));
                sa = __builtin_amdgcn_mfma_f32_32x32x16_f16(kf, qf[m], sa, 0, 0, 0);
            }
            float p[16];
#pragma unroll
            for (int r = 0; r < 16; ++r) p[r] = __builtin_amdgcn_exp2f(sa[r]);
            // C-layout k of reg r (rel. 16-key chunk): (r&3) + 8*(r>>2) + 4*hi.
            // A-frag word w = keys (hi*8+2w, hi*8+2w+1):
            //   swap(pk(p0,p1), pk(p4,p5)) -> w0, w2 ; swap(pk(p2,p3), pk(p6,p7)) -> w1, w3
#pragma unroll
            for (int kh = 0; kh < 2; ++kh) {
                unsigned w0 = pk2(p[kh * 8 + 0], p[kh * 8 + 1]);
                unsigned w2 = pk2(p[kh * 8 + 4], p[kh * 8 + 5]);
                unsigned w1 = pk2(p[kh * 8 + 2], p[kh * 8 + 3]);
                unsigned w3 = pk2(p[kh * 8 + 6], p[kh * 8 + 7]);
                plswap(w0, w2);
                plswap(w1, w3);
                union { unsigned u[4]; half8 hh; } cv;
                cv.u[0] = w0; cv.u[1] = w1; cv.u[2] = w2; cv.u[3] = w3;
                pa[st * 2 + kh] = cv.hh;
            }
        }

        // l += P . maskcol (all 32 output cols identical = l[q-row])
#pragma unroll
        for (int c = 0; c < 4; ++c)
            lacc = __builtin_amdgcn_mfma_f32_32x32x16_f16(pa[c], bm[c], lacc, 0, 0, 0);

        // O += P V  (V B-frags from registers)
#pragma unroll
        for (int c = 0; c < 4; ++c) {
            o0 = __builtin_amdgcn_mfma_f32_32x32x16_f16(pa[c], vfr[0][c], o0, 0, 0, 0);
            o1 = __builtin_amdgcn_mfma_f32_32x32x16_f16(pa[c], vfr[1][c], o1, 0, 0, 0);
        }
    }

    // Epilogue: C row r -> q = q0w + (r&3) + 8*(r>>2) + 4*hi; l[q] = lacc[r]
    // (present in every lane). Cols: d = nt*32 + l31.
#pragma unroll
    for (int r = 0; r < 16; ++r) {
        int q = q0w + (r & 3) + 8 * (r >> 2) + 4 * hi;
        float lv = lacc[r];
        float iv = (mrow[q] != 0 && lv > 0.f) ? (1.0f / lv) : 0.f;
        float* orow = out + ((size_t)(b * T_ + q)) * C_ + h * DH_;
        orow[l31]      = o0[r] * iv;
        orow[32 + l31] = o1[r] * iv;
    }
}

// ---------------------------------------------------------------------------
extern "C" void kernel_launch(void* const* d_in, const int* in_sizes, int n_in,
                              void* d_out, int out_size, void* d_ws, size_t ws_size,
                              hipStream_t stream)
{
    (void)in_sizes; (void)n_in; (void)out_size; (void)ws_size;
    const float* x  = (const float*)d_in[0];
    const float* Wq = (const float*)d_in[1];
    const float* bq = (const float*)d_in[2];
    const float* Wk = (const float*)d_in[3];
    const float* bk = (const float*)d_in[4];
    const float* Wv = (const float*)d_in[5];
    const float* bv = (const float*)d_in[6];
    const int* mask = (const int*)d_in[7];
    float* out = (float*)d_out;

    const size_t NX = (size_t)B_ * T_ * C_;          // 4 Mi elements
    unsigned short* xf = (unsigned short*)d_ws;       // 8 MB fp16 x
    unsigned short* wt = xf + NX;                     // 6 MB fp16 W^T x3
    unsigned short* qb = wt + (size_t)3 * C_ * C_;    // 8 MB (pre-scaled q)
    unsigned short* kb = qb + NX;                     // 8 MB
    unsigned short* vt = kb + NX;                     // 8 MB
    unsigned short* mb = vt + NX;                     // 8 KB

    prep_kernel<<<5120, 256, 0, stream>>>(x, xf, mask, mb, Wq, Wk, Wv, wt);
    qkv_mfma_kernel<<<dim3(32, 8, 3), 256, 0, stream>>>(
        xf, wt, bq, bk, bv, mask, qb, kb, vt);
    attn_mfma_kernel<<<dim3(32, 16), 256, 0, stream>>>(qb, kb, vt, mask, mb, out);
}

// Round 5
// 170.928 us; speedup vs baseline: 1.8174x; 1.1418x over previous
//
#include <hip/hip_runtime.h>

#define B_ 2
#define T_ 2048
#define C_ 1024
#define H_ 16
#define DH_ 64

typedef __attribute__((ext_vector_type(8))) _Float16 half8;  // 8 f16 (4 VGPRs)
typedef __attribute__((ext_vector_type(4))) _Float16 half4;  // 4 f16 (2 VGPRs)
typedef __attribute__((ext_vector_type(2))) __fp16 fp16x2;   // cvt_pkrtz result type
typedef __attribute__((ext_vector_type(4))) float f32x4;
typedef __attribute__((ext_vector_type(16))) float f32x16;

__device__ __forceinline__ unsigned short f2h(float f) {
    union { _Float16 h; unsigned short u; } cv; cv.h = (_Float16)f; return cv.u;
}
__device__ __forceinline__ unsigned pk2(float a, float b) {
    union { fp16x2 h; unsigned u; } cv;
    cv.h = __builtin_amdgcn_cvt_pkrtz(a, b);
    return cv.u;
}
// swap lanes 32-63 of a with lanes 0-31 of b (gfx950)
__device__ __forceinline__ void plswap(unsigned &a, unsigned &b) {
    asm volatile("v_permlane32_swap_b32 %0, %1" : "+v"(a), "+v"(b));
}

__device__ __forceinline__ void gll16(const void* g, void* l) {
    __builtin_amdgcn_global_load_lds(
        (const __attribute__((address_space(1))) void*)g,
        (__attribute__((address_space(3))) void*)l, 16, 0, 0);
}

// ---------------------------------------------------------------------------
// Prep (single launch): blocks [0,2048): x fp32->fp16 (+mask vec in block 0);
// blocks [2048, 5120): W transpose+convert -> Wt[z] (fp16 [N][K]).
// ---------------------------------------------------------------------------
__global__ __launch_bounds__(256) void prep_kernel(
    const float* __restrict__ x, unsigned short* __restrict__ xf,
    const int* __restrict__ mask, unsigned short* __restrict__ mb,
    const float* __restrict__ Wq, const float* __restrict__ Wk,
    const float* __restrict__ Wv, unsigned short* __restrict__ wt)
{
    __shared__ float tile[32][33];
    const int tid = threadIdx.x;

    if (blockIdx.x < 2048) {
        const size_t idx8 = ((size_t)blockIdx.x * 256 + tid) * 8;
        float4 v0 = *(const float4*)(x + idx8);
        float4 v1 = *(const float4*)(x + idx8 + 4);
        float f[8] = {v0.x, v0.y, v0.z, v0.w, v1.x, v1.y, v1.z, v1.w};
        unsigned short h[8];
#pragma unroll
        for (int i = 0; i < 8; i++) h[i] = f2h(f[i]);
        *(uint4*)(xf + idx8) = *(const uint4*)h;

        if (blockIdx.x == 0) {
#pragma unroll
            for (int j = 0; j < 16; j++) {
                int i = tid * 16 + j;               // covers B_*T_ = 4096
                mb[i] = (mask[i] != 0) ? (unsigned short)0x3C00 : (unsigned short)0;
            }
        }
    } else {
        const int idx = blockIdx.x - 2048;
        const int z   = idx >> 10;
        const int rem = idx & 1023;
        const int n0  = (rem & 31) * 32;
        const int k0  = (rem >> 5) * 32;
        const float* __restrict__ W = (z == 0) ? Wq : (z == 1) ? Wk : Wv;
        unsigned short* __restrict__ wtz = wt + (size_t)z * C_ * C_;
        const int tx = tid & 31;
        const int ty = tid >> 5;                    // 0..7
#pragma unroll
        for (int j = 0; j < 4; j++)
            tile[ty + j * 8][tx] = W[(size_t)(k0 + ty + j * 8) * C_ + n0 + tx];
        __syncthreads();
#pragma unroll
        for (int j = 0; j < 4; j++)
            wtz[(size_t)(n0 + ty + j * 8) * C_ + k0 + tx] = f2h(tile[tx][ty + j * 8]);
    }
}

// ---------------------------------------------------------------------------
// QKV projection (R12 in-block structure) + R21 XCD-locality swizzle.
// Grid flattened to 768; virt = (bid&7)*96 + (bid>>3) gives XCD i the
// (y,z) pairs [3i,3i+3) x all 32 tok-blocks: W working set per XCD =
// 3 x 256KB (L2-resident, 32x reuse); X slices hit L2 via the ~96
// concurrent blocks per XCD. Cuts L3->L2 staging ~384MB -> ~70MB.
// ---------------------------------------------------------------------------
__global__ __launch_bounds__(256) void qkv_mfma_kernel(
    const unsigned short* __restrict__ xf, const unsigned short* __restrict__ wt,
    const float* __restrict__ bq, const float* __restrict__ bk,
    const float* __restrict__ bv, const int* __restrict__ maskp,
    unsigned short* __restrict__ qb, unsigned short* __restrict__ kb,
    unsigned short* __restrict__ vt)
{
    __shared__ unsigned short sX[128 * 64];
    __shared__ unsigned short sW[128 * 64];

    const int bid  = blockIdx.x;
    const int virt = (bid & 7) * 96 + (bid >> 3);
    const int yz   = virt >> 5;          // 0..23 : 3 per XCD
    const int tokb = virt & 31;          // 0..31
    const int z    = yz >> 3;            // 0..2
    const int yb   = yz & 7;             // 0..7

    const float* __restrict__ bias = (z == 0) ? bq : (z == 1) ? bk : bv;
    const unsigned short* __restrict__ wtz = wt + (size_t)z * C_ * C_;

    const int tok0 = tokb * 128;
    const int col0 = yb * 128;
    const int wv    = threadIdx.x >> 6;
    const int lane  = threadIdx.x & 63;
    const int l15   = lane & 15;
    const int quad  = lane >> 4;
    const int l7    = l15 & 7;
    const int wm    = wv >> 1;
    const int wn    = wv & 1;
    const int lrow8 = lane >> 3;
    const int gch   = (lane & 7) ^ lrow8;

    f32x4 acc[4][4];
#pragma unroll
    for (int i = 0; i < 4; i++)
#pragma unroll
        for (int j = 0; j < 4; j++) acc[i][j] = (f32x4){0.f, 0.f, 0.f, 0.f};

    int aoff[4][2], boff[4][2];
#pragma unroll
    for (int i = 0; i < 4; i++)
#pragma unroll
        for (int s = 0; s < 2; s++) {
            aoff[i][s] = (wm * 64 + i * 16 + l15) * 64 + (((s * 4 + quad) ^ l7) * 8);
            boff[i][s] = (wn * 64 + i * 16 + l15) * 64 + (((s * 4 + quad) ^ l7) * 8);
        }

    const unsigned short* Abuf = (z < 2) ? sX : sW;
    const unsigned short* Bbuf = (z < 2) ? sW : sX;

    for (int k0 = 0; k0 < C_; k0 += 64) {
        __syncthreads();
#pragma unroll
        for (int s = 0; s < 8; ++s) {
            int g    = (s << 2) + wv;
            int tsel = g >> 4;
            int r0   = (g & 15) << 3;
            const unsigned short* src = tsel ? wtz : xf;
            unsigned short*       dst = tsel ? sW  : sX;
            int rowg = tsel ? col0 : tok0;
            gll16(src + (size_t)(rowg + r0 + lrow8) * C_ + k0 + gch * 8,
                  dst + r0 * 64);
        }
        __syncthreads();

        half8 af[4][2], bf_[4][2];
#pragma unroll
        for (int i = 0; i < 4; i++)
#pragma unroll
            for (int s = 0; s < 2; s++) {
                af[i][s]  = *(const half8*)&Abuf[aoff[i][s]];
                bf_[i][s] = *(const half8*)&Bbuf[boff[i][s]];
            }
#pragma unroll
        for (int s = 0; s < 2; s++)
#pragma unroll
            for (int j = 0; j < 4; j++)
#pragma unroll
                for (int i = 0; i < 4; i++)
                    acc[i][j] = __builtin_amdgcn_mfma_f32_16x16x32_f16(
                        af[i][s], bf_[j][s], acc[i][j], 0, 0, 0);
    }

    if (z == 0) {
#pragma unroll
        for (int j = 0; j < 4; j++) {
            int col = col0 + wn * 64 + j * 16 + l15;
            int h = col >> 6, d = col & 63;
            float bs = bias[col];
#pragma unroll
            for (int i = 0; i < 4; i++) {
#pragma unroll
                for (int r = 0; r < 4; r++) {
                    int tok = tok0 + wm * 64 + i * 16 + quad * 4 + r;
                    int bidx = tok >> 11, t = tok & (T_ - 1);
                    qb[((size_t)(bidx * H_ + h) * T_ + t) * DH_ + d] =
                        f2h((acc[i][j][r] + bs) * 0.18033688011112042f);
                }
            }
        }
    } else if (z == 1) {
#pragma unroll
        for (int j = 0; j < 4; j++) {
            int col = col0 + wn * 64 + j * 16 + l15;
            int h = col >> 6, d = col & 63;
            float bs = bias[col];
#pragma unroll
            for (int i = 0; i < 4; i++) {
#pragma unroll
                for (int r = 0; r < 4; r++) {
                    int tok = tok0 + wm * 64 + i * 16 + quad * 4 + r;
                    int bidx = tok >> 11, t = tok & (T_ - 1);
                    kb[((size_t)(bidx * H_ + h) * T_ + t) * DH_ + d] =
                        f2h(acc[i][j][r] + bs);
                }
            }
        }
    } else {
        float mv4[4]; int bidx4[4], t4[4];
#pragma unroll
        for (int j = 0; j < 4; j++) {
            int tok = tok0 + wn * 64 + j * 16 + l15;
            bidx4[j] = tok >> 11; t4[j] = tok & (T_ - 1);
            mv4[j] = (maskp[bidx4[j] * T_ + t4[j]] != 0) ? 1.f : 0.f;
        }
#pragma unroll
        for (int i = 0; i < 4; i++) {
#pragma unroll
            for (int r = 0; r < 4; r++) {
                int col = col0 + wm * 64 + i * 16 + quad * 4 + r;
                int h = col >> 6, d = col & 63;
                float bs = bias[col];
#pragma unroll
                for (int j = 0; j < 4; j++) {
                    vt[((size_t)(bidx4[j] * H_ + h) * DH_ + d) * T_ + t4[j]] =
                        f2h((acc[i][j][r] + bs) * mv4[j]);
                }
            }
        }
    }
}

// ---------------------------------------------------------------------------
// Attention (R18/R2 verbatim — best measured 53.2us): 32x32x16, 4 waves x 32 q,
// K and V double-buffered in LDS, register-only P path via cvt_pkrtz +
// permlane32_swap, l via all-columns mask MFMA. R3 (split-K) and R4 (V from
// global) both regressed — keep this structure.
// ---------------------------------------------------------------------------
__global__ __launch_bounds__(256, 2) void attn_mfma_kernel(
    const unsigned short* __restrict__ qb,  // [32][2048][64] f16 (pre-scaled)
    const unsigned short* __restrict__ kb,  // [32][2048][64] f16
    const unsigned short* __restrict__ vt,  // [32][64][2048] f16 (mask-zeroed)
    const int* __restrict__ mask,           // [2][2048]
    const unsigned short* __restrict__ mb,  // [2][2048] f16 {0,1}
    float* __restrict__ out)                // [2][2048][1024]
{
    __shared__ unsigned short Ks[2][64 * 64];
    __shared__ unsigned short Vs[2][64 * 64];

    const int bh   = blockIdx.x;            // bh-major: same head -> same XCD
    const int b    = bh >> 4;
    const int h    = bh & 15;
    const int wv   = threadIdx.x >> 6;      // 0..3
    const int lane = threadIdx.x & 63;
    const int l31  = lane & 31;
    const int hi   = lane >> 5;
    const int l7b  = l31 & 7;               // row&7 for swizzled frag reads
    const int q0w  = blockIdx.y * 128 + wv * 32;

    const unsigned short* kbh = kb + (size_t)bh * T_ * DH_;
    const unsigned short* vbh = vt + (size_t)bh * DH_ * T_;
    const unsigned short* mbb = mb + b * T_;
    const int* __restrict__ mrow = mask + b * T_;

    // Q B-frags (32x32x16): B[k=dh][n=q]: lane n=l31, k = hi*8+j per m-chunk
    half8 qf[4];
#pragma unroll
    for (int m = 0; m < 4; ++m)
        qf[m] = *(const half8*)(qb + ((size_t)bh * T_ + q0w + l31) * DH_
                                + m * 16 + hi * 8);

    f32x16 o0, o1, lacc;
#pragma unroll
    for (int r = 0; r < 16; ++r) { o0[r] = 0.f; o1[r] = 0.f; lacc[r] = 0.f; }

    const int lrow = lane >> 3;
    const int gch  = (lane & 7) ^ lrow;

#pragma unroll
    for (int s = 0; s < 4; ++s) {
        int j  = (wv << 2) + s;
        int rb = j & 7;
        if (j < 8) gll16(kbh + (size_t)(rb * 8 + lrow) * DH_ + gch * 8, &Ks[0][rb * 512]);
        else       gll16(vbh + (size_t)(rb * 8 + lrow) * T_  + gch * 8, &Vs[0][rb * 512]);
    }

    for (int kt = 0; kt < 32; ++kt) {
        const int cur   = kt & 1;
        const int kbase = kt * 64;
        __syncthreads();

        if (kt < 31) {
            const int nb = kbase + 64;
#pragma unroll
            for (int s = 0; s < 4; ++s) {
                int j  = (wv << 2) + s;
                int rb = j & 7;
                if (j < 8) gll16(kbh + (size_t)(nb + rb * 8 + lrow) * DH_ + gch * 8,
                                 &Ks[cur ^ 1][rb * 512]);
                else       gll16(vbh + (size_t)(rb * 8 + lrow) * T_ + nb + gch * 8,
                                 &Vs[cur ^ 1][rb * 512]);
            }
        }

        const unsigned short* Kc = &Ks[cur][0];
        const unsigned short* Vc = &Vs[cur][0];

        // mask B-frags for l-sum: every column n holds m[k]; k = chunk*16+hi*8+j
        half8 bm[4];
#pragma unroll
        for (int c = 0; c < 4; ++c)
            bm[c] = *(const half8*)(mbb + kbase + c * 16 + hi * 8);

        // S^T = K . Q^T per 32-key tile; exp2; pack to A-frags in registers.
        half8 pa[4];
#pragma unroll
        for (int st = 0; st < 2; ++st) {
            f32x16 sa;
#pragma unroll
            for (int r = 0; r < 16; ++r) sa[r] = 0.f;
#pragma unroll
            for (int m = 0; m < 4; ++m) {
                half8 kf = *(const half8*)(Kc + (st * 32 + l31) * 64
                                           + (((m * 2 + hi) ^ l7b) * 8));
                sa = __builtin_amdgcn_mfma_f32_32x32x16_f16(kf, qf[m], sa, 0, 0, 0);
            }
            float p[16];
#pragma unroll
            for (int r = 0; r < 16; ++r) p[r] = __builtin_amdgcn_exp2f(sa[r]);
            // C-layout k of reg r (rel. 16-key chunk): (r&3) + 8*(r>>2) + 4*hi.
            // A-frag word w = keys (hi*8+2w, hi*8+2w+1):
            //   swap(pk(p0,p1), pk(p4,p5)) -> w0, w2 ; swap(pk(p2,p3), pk(p6,p7)) -> w1, w3
#pragma unroll
            for (int kh = 0; kh < 2; ++kh) {
                unsigned w0 = pk2(p[kh * 8 + 0], p[kh * 8 + 1]);
                unsigned w2 = pk2(p[kh * 8 + 4], p[kh * 8 + 5]);
                unsigned w1 = pk2(p[kh * 8 + 2], p[kh * 8 + 3]);
                unsigned w3 = pk2(p[kh * 8 + 6], p[kh * 8 + 7]);
                plswap(w0, w2);
                plswap(w1, w3);
                union { unsigned u[4]; half8 hh; } cv;
                cv.u[0] = w0; cv.u[1] = w1; cv.u[2] = w2; cv.u[3] = w3;
                pa[st * 2 + kh] = cv.hh;
            }
        }

        // l += P . maskcol (all 32 output cols identical = l[q-row])
#pragma unroll
        for (int c = 0; c < 4; ++c)
            lacc = __builtin_amdgcn_mfma_f32_32x32x16_f16(pa[c], bm[c], lacc, 0, 0, 0);

        // O += P V  (V B-frags: n = d = l31 (+32), k = keys c*16+hi*8+j)
#pragma unroll
        for (int c = 0; c < 4; ++c) {
            half8 v0 = *(const half8*)(Vc + (l31) * 64      + (((c * 2 + hi) ^ l7b) * 8));
            half8 v1 = *(const half8*)(Vc + (32 + l31) * 64 + (((c * 2 + hi) ^ l7b) * 8));
            o0 = __builtin_amdgcn_mfma_f32_32x32x16_f16(pa[c], v0, o0, 0, 0, 0);
            o1 = __builtin_amdgcn_mfma_f32_32x32x16_f16(pa[c], v1, o1, 0, 0, 0);
        }
    }

    // Epilogue: C row r -> q = q0w + (r&3) + 8*(r>>2) + 4*hi; l[q] = lacc[r]
    // (present in every lane). Cols: d = nt*32 + l31.
#pragma unroll
    for (int r = 0; r < 16; ++r) {
        int q = q0w + (r & 3) + 8 * (r >> 2) + 4 * hi;
        float lv = lacc[r];
        float iv = (mrow[q] != 0 && lv > 0.f) ? (1.0f / lv) : 0.f;
        float* orow = out + ((size_t)(b * T_ + q)) * C_ + h * DH_;
        orow[l31]      = o0[r] * iv;
        orow[32 + l31] = o1[r] * iv;
    }
}

// ---------------------------------------------------------------------------
extern "C" void kernel_launch(void* const* d_in, const int* in_sizes, int n_in,
                              void* d_out, int out_size, void* d_ws, size_t ws_size,
                              hipStream_t stream)
{
    (void)in_sizes; (void)n_in; (void)out_size; (void)ws_size;
    const float* x  = (const float*)d_in[0];
    const float* Wq = (const float*)d_in[1];
    const float* bq = (const float*)d_in[2];
    const float* Wk = (const float*)d_in[3];
    const float* bk = (const float*)d_in[4];
    const float* Wv = (const float*)d_in[5];
    const float* bv = (const float*)d_in[6];
    const int* mask = (const int*)d_in[7];
    float* out = (float*)d_out;

    const size_t NX = (size_t)B_ * T_ * C_;          // 4 Mi elements
    unsigned short* xf = (unsigned short*)d_ws;       // 8 MB fp16 x
    unsigned short* wt = xf + NX;                     // 6 MB fp16 W^T x3
    unsigned short* qb = wt + (size_t)3 * C_ * C_;    // 8 MB (pre-scaled q)
    unsigned short* kb = qb + NX;                     // 8 MB
    unsigned short* vt = kb + NX;                     // 8 MB
    unsigned short* mb = vt + NX;                     // 8 KB

    prep_kernel<<<5120, 256, 0, stream>>>(x, xf, mask, mb, Wq, Wk, Wv, wt);
    qkv_mfma_kernel<<<768, 256, 0, stream>>>(
        xf, wt, bq, bk, bv, mask, qb, kb, vt);
    attn_mfma_kernel<<<dim3(32, 16), 256, 0, stream>>>(qb, kb, vt, mask, mb, out);
}

// Round 6
// 167.303 us; speedup vs baseline: 1.8568x; 1.0217x over previous
//
#include <hip/hip_runtime.h>

#define B_ 2
#define T_ 2048
#define C_ 1024
#define H_ 16
#define DH_ 64

typedef __attribute__((ext_vector_type(8))) _Float16 half8;  // 8 f16 (4 VGPRs)
typedef __attribute__((ext_vector_type(4))) _Float16 half4;  // 4 f16 (2 VGPRs)
typedef __attribute__((ext_vector_type(2))) __fp16 fp16x2;   // cvt_pkrtz result type
typedef __attribute__((ext_vector_type(4))) float f32x4;
typedef __attribute__((ext_vector_type(16))) float f32x16;

__device__ __forceinline__ unsigned short f2h(float f) {
    union { _Float16 h; unsigned short u; } cv; cv.h = (_Float16)f; return cv.u;
}
__device__ __forceinline__ unsigned pk2(float a, float b) {
    union { fp16x2 h; unsigned u; } cv;
    cv.h = __builtin_amdgcn_cvt_pkrtz(a, b);
    return cv.u;
}
// swap lanes 32-63 of a with lanes 0-31 of b (gfx950)
__device__ __forceinline__ void plswap(unsigned &a, unsigned &b) {
    asm volatile("v_permlane32_swap_b32 %0, %1" : "+v"(a), "+v"(b));
}

__device__ __forceinline__ void gll16(const void* g, void* l) {
    __builtin_amdgcn_global_load_lds(
        (const __attribute__((address_space(1))) void*)g,
        (__attribute__((address_space(3))) void*)l, 16, 0, 0);
}

// ---------------------------------------------------------------------------
// Prep (single launch): blocks [0,2048): x fp32->fp16 (+mask vec in block 0);
// blocks [2048, 5120): W transpose+convert -> Wt[z] (fp16 [N][K]).
// ---------------------------------------------------------------------------
__global__ __launch_bounds__(256) void prep_kernel(
    const float* __restrict__ x, unsigned short* __restrict__ xf,
    const int* __restrict__ mask, unsigned short* __restrict__ mb,
    const float* __restrict__ Wq, const float* __restrict__ Wk,
    const float* __restrict__ Wv, unsigned short* __restrict__ wt)
{
    __shared__ float tile[32][33];
    const int tid = threadIdx.x;

    if (blockIdx.x < 2048) {
        const size_t idx8 = ((size_t)blockIdx.x * 256 + tid) * 8;
        float4 v0 = *(const float4*)(x + idx8);
        float4 v1 = *(const float4*)(x + idx8 + 4);
        float f[8] = {v0.x, v0.y, v0.z, v0.w, v1.x, v1.y, v1.z, v1.w};
        unsigned short h[8];
#pragma unroll
        for (int i = 0; i < 8; i++) h[i] = f2h(f[i]);
        *(uint4*)(xf + idx8) = *(const uint4*)h;

        if (blockIdx.x == 0) {
#pragma unroll
            for (int j = 0; j < 16; j++) {
                int i = tid * 16 + j;               // covers B_*T_ = 4096
                mb[i] = (mask[i] != 0) ? (unsigned short)0x3C00 : (unsigned short)0;
            }
        }
    } else {
        const int idx = blockIdx.x - 2048;
        const int z   = idx >> 10;
        const int rem = idx & 1023;
        const int n0  = (rem & 31) * 32;
        const int k0  = (rem >> 5) * 32;
        const float* __restrict__ W = (z == 0) ? Wq : (z == 1) ? Wk : Wv;
        unsigned short* __restrict__ wtz = wt + (size_t)z * C_ * C_;
        const int tx = tid & 31;
        const int ty = tid >> 5;                    // 0..7
#pragma unroll
        for (int j = 0; j < 4; j++)
            tile[ty + j * 8][tx] = W[(size_t)(k0 + ty + j * 8) * C_ + n0 + tx];
        __syncthreads();
#pragma unroll
        for (int j = 0; j < 4; j++)
            wtz[(size_t)(n0 + ty + j * 8) * C_ + k0 + tx] = f2h(tile[tx][ty + j * 8]);
    }
}

// ---------------------------------------------------------------------------
// QKV projection R22. Two changes vs R21 (FETCH was 68.7MB = exactly the
// 70MB floor of the R21 partition; all pipes <21% -> staging latency
// serially exposed):
// 1) 2D XCD tiling: XCD i owns 8 tok-blocks x 12 yz-pairs (traffic-minimal
//    8+12=20 slices/XCD = 5MB -> ~40MB total L2 fill). yz-inner order keeps
//    hot set (W 3MB + X 256KB) < 4MB L2.
// 2) Double-buffered LDS (64KB): barrier -> issue STAGE(t+1) -> compute(t);
//    next tile's loads fly under the ~2000cy compute phase instead of being
//    drained serially at a back-to-back barrier pair.
// ---------------------------------------------------------------------------
__global__ __launch_bounds__(256) void qkv_mfma_kernel(
    const unsigned short* __restrict__ xf, const unsigned short* __restrict__ wt,
    const float* __restrict__ bq, const float* __restrict__ bk,
    const float* __restrict__ bv, const int* __restrict__ maskp,
    unsigned short* __restrict__ qb, unsigned short* __restrict__ kb,
    unsigned short* __restrict__ vt)
{
    __shared__ unsigned short sX[2][128 * 64];
    __shared__ unsigned short sW[2][128 * 64];

    const int bid  = blockIdx.x;
    const int xcd  = bid & 7;            // HW: block bid runs on XCD bid%8
    const int idx  = bid >> 3;           // 0..95 within XCD
    const int tokl = idx / 12;           // 0..7  (tok-local, outer)
    const int yzl  = idx % 12;           // 0..11 (yz-local, inner -> W hot)
    const int tokb = (xcd >> 1) * 8 + tokl;   // 0..31
    const int yz   = (xcd & 1) * 12 + yzl;    // 0..23
    const int z    = yz >> 3;            // 0..2
    const int yb   = yz & 7;             // 0..7

    const float* __restrict__ bias = (z == 0) ? bq : (z == 1) ? bk : bv;
    const unsigned short* __restrict__ wtz = wt + (size_t)z * C_ * C_;

    const int tok0 = tokb * 128;
    const int col0 = yb * 128;
    const int wv    = threadIdx.x >> 6;
    const int lane  = threadIdx.x & 63;
    const int l15   = lane & 15;
    const int quad  = lane >> 4;
    const int l7    = l15 & 7;
    const int wm    = wv >> 1;
    const int wn    = wv & 1;
    const int lrow8 = lane >> 3;
    const int gch   = (lane & 7) ^ lrow8;

    f32x4 acc[4][4];
#pragma unroll
    for (int i = 0; i < 4; i++)
#pragma unroll
        for (int j = 0; j < 4; j++) acc[i][j] = (f32x4){0.f, 0.f, 0.f, 0.f};

    int aoff[4][2], boff[4][2];
#pragma unroll
    for (int i = 0; i < 4; i++)
#pragma unroll
        for (int s = 0; s < 2; s++) {
            aoff[i][s] = (wm * 64 + i * 16 + l15) * 64 + (((s * 4 + quad) ^ l7) * 8);
            boff[i][s] = (wn * 64 + i * 16 + l15) * 64 + (((s * 4 + quad) ^ l7) * 8);
        }

#define STAGE_QKV(k0v, bi) do {                                               \
    _Pragma("unroll")                                                         \
    for (int s = 0; s < 8; ++s) {                                             \
        int g    = (s << 2) + wv;                                             \
        int tsel = g >> 4;                                                    \
        int r0   = (g & 15) << 3;                                             \
        const unsigned short* src = tsel ? wtz : xf;                          \
        unsigned short*       dst = tsel ? &sW[bi][0] : &sX[bi][0];           \
        int rowg = tsel ? col0 : tok0;                                        \
        gll16(src + (size_t)(rowg + r0 + lrow8) * C_ + (k0v) + gch * 8,       \
              dst + r0 * 64);                                                 \
    }                                                                         \
} while (0)

    STAGE_QKV(0, 0);

    for (int k0 = 0; k0 < C_; k0 += 64) {
        const int cur = (k0 >> 6) & 1;
        __syncthreads();                 // drains vmcnt(0): buf[cur] ready
        if (k0 + 64 < C_) STAGE_QKV(k0 + 64, cur ^ 1);

        const unsigned short* Abuf = (z < 2) ? &sX[cur][0] : &sW[cur][0];
        const unsigned short* Bbuf = (z < 2) ? &sW[cur][0] : &sX[cur][0];

        half8 af[4][2], bf_[4][2];
#pragma unroll
        for (int i = 0; i < 4; i++)
#pragma unroll
            for (int s = 0; s < 2; s++) {
                af[i][s]  = *(const half8*)&Abuf[aoff[i][s]];
                bf_[i][s] = *(const half8*)&Bbuf[boff[i][s]];
            }
#pragma unroll
        for (int s = 0; s < 2; s++)
#pragma unroll
            for (int j = 0; j < 4; j++)
#pragma unroll
                for (int i = 0; i < 4; i++)
                    acc[i][j] = __builtin_amdgcn_mfma_f32_16x16x32_f16(
                        af[i][s], bf_[j][s], acc[i][j], 0, 0, 0);
    }
#undef STAGE_QKV

    if (z == 0) {
#pragma unroll
        for (int j = 0; j < 4; j++) {
            int col = col0 + wn * 64 + j * 16 + l15;
            int h = col >> 6, d = col & 63;
            float bs = bias[col];
#pragma unroll
            for (int i = 0; i < 4; i++) {
#pragma unroll
                for (int r = 0; r < 4; r++) {
                    int tok = tok0 + wm * 64 + i * 16 + quad * 4 + r;
                    int bidx = tok >> 11, t = tok & (T_ - 1);
                    qb[((size_t)(bidx * H_ + h) * T_ + t) * DH_ + d] =
                        f2h((acc[i][j][r] + bs) * 0.18033688011112042f);
                }
            }
        }
    } else if (z == 1) {
#pragma unroll
        for (int j = 0; j < 4; j++) {
            int col = col0 + wn * 64 + j * 16 + l15;
            int h = col >> 6, d = col & 63;
            float bs = bias[col];
#pragma unroll
            for (int i = 0; i < 4; i++) {
#pragma unroll
                for (int r = 0; r < 4; r++) {
                    int tok = tok0 + wm * 64 + i * 16 + quad * 4 + r;
                    int bidx = tok >> 11, t = tok & (T_ - 1);
                    kb[((size_t)(bidx * H_ + h) * T_ + t) * DH_ + d] =
                        f2h(acc[i][j][r] + bs);
                }
            }
        }
    } else {
        float mv4[4]; int bidx4[4], t4[4];
#pragma unroll
        for (int j = 0; j < 4; j++) {
            int tok = tok0 + wn * 64 + j * 16 + l15;
            bidx4[j] = tok >> 11; t4[j] = tok & (T_ - 1);
            mv4[j] = (maskp[bidx4[j] * T_ + t4[j]] != 0) ? 1.f : 0.f;
        }
#pragma unroll
        for (int i = 0; i < 4; i++) {
#pragma unroll
            for (int r = 0; r < 4; r++) {
                int col = col0 + wm * 64 + i * 16 + quad * 4 + r;
                int h = col >> 6, d = col & 63;
                float bs = bias[col];
#pragma unroll
                for (int j = 0; j < 4; j++) {
                    vt[((size_t)(bidx4[j] * H_ + h) * DH_ + d) * T_ + t4[j]] =
                        f2h((acc[i][j][r] + bs) * mv4[j]);
                }
            }
        }
    }
}

// ---------------------------------------------------------------------------
// Attention (R18/R2 verbatim — best measured 53.2us): 32x32x16, 4 waves x 32 q,
// K and V double-buffered in LDS, register-only P path via cvt_pkrtz +
// permlane32_swap, l via all-columns mask MFMA. R3 (split-K) and R4 (V from
// global) both regressed — keep this structure.
// ---------------------------------------------------------------------------
__global__ __launch_bounds__(256, 2) void attn_mfma_kernel(
    const unsigned short* __restrict__ qb,  // [32][2048][64] f16 (pre-scaled)
    const unsigned short* __restrict__ kb,  // [32][2048][64] f16
    const unsigned short* __restrict__ vt,  // [32][64][2048] f16 (mask-zeroed)
    const int* __restrict__ mask,           // [2][2048]
    const unsigned short* __restrict__ mb,  // [2][2048] f16 {0,1}
    float* __restrict__ out)                // [2][2048][1024]
{
    __shared__ unsigned short Ks[2][64 * 64];
    __shared__ unsigned short Vs[2][64 * 64];

    const int bh   = blockIdx.x;            // bh-major: same head -> same XCD
    const int b    = bh >> 4;
    const int h    = bh & 15;
    const int wv   = threadIdx.x >> 6;      // 0..3
    const int lane = threadIdx.x & 63;
    const int l31  = lane & 31;
    const int hi   = lane >> 5;
    const int l7b  = l31 & 7;               // row&7 for swizzled frag reads
    const int q0w  = blockIdx.y * 128 + wv * 32;

    const unsigned short* kbh = kb + (size_t)bh * T_ * DH_;
    const unsigned short* vbh = vt + (size_t)bh * DH_ * T_;
    const unsigned short* mbb = mb + b * T_;
    const int* __restrict__ mrow = mask + b * T_;

    // Q B-frags (32x32x16): B[k=dh][n=q]: lane n=l31, k = hi*8+j per m-chunk
    half8 qf[4];
#pragma unroll
    for (int m = 0; m < 4; ++m)
        qf[m] = *(const half8*)(qb + ((size_t)bh * T_ + q0w + l31) * DH_
                                + m * 16 + hi * 8);

    f32x16 o0, o1, lacc;
#pragma unroll
    for (int r = 0; r < 16; ++r) { o0[r] = 0.f; o1[r] = 0.f; lacc[r] = 0.f; }

    const int lrow = lane >> 3;
    const int gch  = (lane & 7) ^ lrow;

#pragma unroll
    for (int s = 0; s < 4; ++s) {
        int j  = (wv << 2) + s;
        int rb = j & 7;
        if (j < 8) gll16(kbh + (size_t)(rb * 8 + lrow) * DH_ + gch * 8, &Ks[0][rb * 512]);
        else       gll16(vbh + (size_t)(rb * 8 + lrow) * T_  + gch * 8, &Vs[0][rb * 512]);
    }

    for (int kt = 0; kt < 32; ++kt) {
        const int cur   = kt & 1;
        const int kbase = kt * 64;
        __syncthreads();

        if (kt < 31) {
            const int nb = kbase + 64;
#pragma unroll
            for (int s = 0; s < 4; ++s) {
                int j  = (wv << 2) + s;
                int rb = j & 7;
                if (j < 8) gll16(kbh + (size_t)(nb + rb * 8 + lrow) * DH_ + gch * 8,
                                 &Ks[cur ^ 1][rb * 512]);
                else       gll16(vbh + (size_t)(rb * 8 + lrow) * T_ + nb + gch * 8,
                                 &Vs[cur ^ 1][rb * 512]);
            }
        }

        const unsigned short* Kc = &Ks[cur][0];
        const unsigned short* Vc = &Vs[cur][0];

        // mask B-frags for l-sum: every column n holds m[k]; k = chunk*16+hi*8+j
        half8 bm[4];
#pragma unroll
        for (int c = 0; c < 4; ++c)
            bm[c] = *(const half8*)(mbb + kbase + c * 16 + hi * 8);

        // S^T = K . Q^T per 32-key tile; exp2; pack to A-frags in registers.
        half8 pa[4];
#pragma unroll
        for (int st = 0; st < 2; ++st) {
            f32x16 sa;
#pragma unroll
            for (int r = 0; r < 16; ++r) sa[r] = 0.f;
#pragma unroll
            for (int m = 0; m < 4; ++m) {
                half8 kf = *(const half8*)(Kc + (st * 32 + l31) * 64
                                           + (((m * 2 + hi) ^ l7b) * 8));
                sa = __builtin_amdgcn_mfma_f32_32x32x16_f16(kf, qf[m], sa, 0, 0, 0);
            }
            float p[16];
#pragma unroll
            for (int r = 0; r < 16; ++r) p[r] = __builtin_amdgcn_exp2f(sa[r]);
            // C-layout k of reg r (rel. 16-key chunk): (r&3) + 8*(r>>2) + 4*hi.
            // A-frag word w = keys (hi*8+2w, hi*8+2w+1):
            //   swap(pk(p0,p1), pk(p4,p5)) -> w0, w2 ; swap(pk(p2,p3), pk(p6,p7)) -> w1, w3
#pragma unroll
            for (int kh = 0; kh < 2; ++kh) {
                unsigned w0 = pk2(p[kh * 8 + 0], p[kh * 8 + 1]);
                unsigned w2 = pk2(p[kh * 8 + 4], p[kh * 8 + 5]);
                unsigned w1 = pk2(p[kh * 8 + 2], p[kh * 8 + 3]);
                unsigned w3 = pk2(p[kh * 8 + 6], p[kh * 8 + 7]);
                plswap(w0, w2);
                plswap(w1, w3);
                union { unsigned u[4]; half8 hh; } cv;
                cv.u[0] = w0; cv.u[1] = w1; cv.u[2] = w2; cv.u[3] = w3;
                pa[st * 2 + kh] = cv.hh;
            }
        }

        // l += P . maskcol (all 32 output cols identical = l[q-row])
#pragma unroll
        for (int c = 0; c < 4; ++c)
            lacc = __builtin_amdgcn_mfma_f32_32x32x16_f16(pa[c], bm[c], lacc, 0, 0, 0);

        // O += P V  (V B-frags: n = d = l31 (+32), k = keys c*16+hi*8+j)
#pragma unroll
        for (int c = 0; c < 4; ++c) {
            half8 v0 = *(const half8*)(Vc + (l31) * 64      + (((c * 2 + hi) ^ l7b) * 8));
            half8 v1 = *(const half8*)(Vc + (32 + l31) * 64 + (((c * 2 + hi) ^ l7b) * 8));
            o0 = __builtin_amdgcn_mfma_f32_32x32x16_f16(pa[c], v0, o0, 0, 0, 0);
            o1 = __builtin_amdgcn_mfma_f32_32x32x16_f16(pa[c], v1, o1, 0, 0, 0);
        }
    }

    // Epilogue: C row r -> q = q0w + (r&3) + 8*(r>>2) + 4*hi; l[q] = lacc[r]
    // (present in every lane). Cols: d = nt*32 + l31.
#pragma unroll
    for (int r = 0; r < 16; ++r) {
        int q = q0w + (r & 3) + 8 * (r >> 2) + 4 * hi;
        float lv = lacc[r];
        float iv = (mrow[q] != 0 && lv > 0.f) ? (1.0f / lv) : 0.f;
        float* orow = out + ((size_t)(b * T_ + q)) * C_ + h * DH_;
        orow[l31]      = o0[r] * iv;
        orow[32 + l31] = o1[r] * iv;
    }
}

// ---------------------------------------------------------------------------
extern "C" void kernel_launch(void* const* d_in, const int* in_sizes, int n_in,
                              void* d_out, int out_size, void* d_ws, size_t ws_size,
                              hipStream_t stream)
{
    (void)in_sizes; (void)n_in; (void)out_size; (void)ws_size;
    const float* x  = (const float*)d_in[0];
    const float* Wq = (const float*)d_in[1];
    const float* bq = (const float*)d_in[2];
    const float* Wk = (const float*)d_in[3];
    const float* bk = (const float*)d_in[4];
    const float* Wv = (const float*)d_in[5];
    const float* bv = (const float*)d_in[6];
    const int* mask = (const int*)d_in[7];
    float* out = (float*)d_out;

    const size_t NX = (size_t)B_ * T_ * C_;          // 4 Mi elements
    unsigned short* xf = (unsigned short*)d_ws;       // 8 MB fp16 x
    unsigned short* wt = xf + NX;                     // 6 MB fp16 W^T x3
    unsigned short* qb = wt + (size_t)3 * C_ * C_;    // 8 MB (pre-scaled q)
    unsigned short* kb = qb + NX;                     // 8 MB
    unsigned short* vt = kb + NX;                     // 8 MB
    unsigned short* mb = vt + NX;                     // 8 KB

    prep_kernel<<<5120, 256, 0, stream>>>(x, xf, mask, mb, Wq, Wk, Wv, wt);
    qkv_mfma_kernel<<<768, 256, 0, stream>>>(
        xf, wt, bq, bk, bv, mask, qb, kb, vt);
    attn_mfma_kernel<<<dim3(32, 16), 256, 0, stream>>>(qb, kb, vt, mask, mb, out);
}

// Round 7
// 166.580 us; speedup vs baseline: 1.8648x; 1.0043x over previous
//
#include <hip/hip_runtime.h>

#define B_ 2
#define T_ 2048
#define C_ 1024
#define H_ 16
#define DH_ 64

typedef __attribute__((ext_vector_type(8))) _Float16 half8;  // 8 f16 (4 VGPRs)
typedef __attribute__((ext_vector_type(4))) _Float16 half4;  // 4 f16 (2 VGPRs)
typedef __attribute__((ext_vector_type(2))) __fp16 fp16x2;   // cvt_pkrtz result type
typedef __attribute__((ext_vector_type(4))) float f32x4;
typedef __attribute__((ext_vector_type(16))) float f32x16;

__device__ __forceinline__ unsigned short f2h(float f) {
    union { _Float16 h; unsigned short u; } cv; cv.h = (_Float16)f; return cv.u;
}
__device__ __forceinline__ unsigned pk2(float a, float b) {
    union { fp16x2 h; unsigned u; } cv;
    cv.h = __builtin_amdgcn_cvt_pkrtz(a, b);
    return cv.u;
}
// swap lanes 32-63 of a with lanes 0-31 of b (gfx950)
__device__ __forceinline__ void plswap(unsigned &a, unsigned &b) {
    asm volatile("v_permlane32_swap_b32 %0, %1" : "+v"(a), "+v"(b));
}

__device__ __forceinline__ void gll16(const void* g, void* l) {
    __builtin_amdgcn_global_load_lds(
        (const __attribute__((address_space(1))) void*)g,
        (__attribute__((address_space(3))) void*)l, 16, 0, 0);
}

// ---------------------------------------------------------------------------
// Prep (single launch): blocks [0,2048): x fp32->fp16 (+mask vec in block 0);
// blocks [2048, 5120): W transpose+convert -> Wt[z] (fp16 [N][K]).
// ---------------------------------------------------------------------------
__global__ __launch_bounds__(256) void prep_kernel(
    const float* __restrict__ x, unsigned short* __restrict__ xf,
    const int* __restrict__ mask, unsigned short* __restrict__ mb,
    const float* __restrict__ Wq, const float* __restrict__ Wk,
    const float* __restrict__ Wv, unsigned short* __restrict__ wt)
{
    __shared__ float tile[32][33];
    const int tid = threadIdx.x;

    if (blockIdx.x < 2048) {
        const size_t idx8 = ((size_t)blockIdx.x * 256 + tid) * 8;
        float4 v0 = *(const float4*)(x + idx8);
        float4 v1 = *(const float4*)(x + idx8 + 4);
        float f[8] = {v0.x, v0.y, v0.z, v0.w, v1.x, v1.y, v1.z, v1.w};
        unsigned short h[8];
#pragma unroll
        for (int i = 0; i < 8; i++) h[i] = f2h(f[i]);
        *(uint4*)(xf + idx8) = *(const uint4*)h;

        if (blockIdx.x == 0) {
#pragma unroll
            for (int j = 0; j < 16; j++) {
                int i = tid * 16 + j;               // covers B_*T_ = 4096
                mb[i] = (mask[i] != 0) ? (unsigned short)0x3C00 : (unsigned short)0;
            }
        }
    } else {
        const int idx = blockIdx.x - 2048;
        const int z   = idx >> 10;
        const int rem = idx & 1023;
        const int n0  = (rem & 31) * 32;
        const int k0  = (rem >> 5) * 32;
        const float* __restrict__ W = (z == 0) ? Wq : (z == 1) ? Wk : Wv;
        unsigned short* __restrict__ wtz = wt + (size_t)z * C_ * C_;
        const int tx = tid & 31;
        const int ty = tid >> 5;                    // 0..7
#pragma unroll
        for (int j = 0; j < 4; j++)
            tile[ty + j * 8][tx] = W[(size_t)(k0 + ty + j * 8) * C_ + n0 + tx];
        __syncthreads();
#pragma unroll
        for (int j = 0; j < 4; j++)
            wtz[(size_t)(n0 + ty + j * 8) * C_ + k0 + tx] = f2h(tile[tx][ty + j * 8]);
    }
}

// ---------------------------------------------------------------------------
// QKV projection R22 (kept from R6): 2D XCD tiling (8 tok x 12 yz per XCD)
// + double-buffered LDS (64KB): barrier -> issue STAGE(t+1) -> compute(t).
// ---------------------------------------------------------------------------
__global__ __launch_bounds__(256) void qkv_mfma_kernel(
    const unsigned short* __restrict__ xf, const unsigned short* __restrict__ wt,
    const float* __restrict__ bq, const float* __restrict__ bk,
    const float* __restrict__ bv, const int* __restrict__ maskp,
    unsigned short* __restrict__ qb, unsigned short* __restrict__ kb,
    unsigned short* __restrict__ vt)
{
    __shared__ unsigned short sX[2][128 * 64];
    __shared__ unsigned short sW[2][128 * 64];

    const int bid  = blockIdx.x;
    const int xcd  = bid & 7;            // HW: block bid runs on XCD bid%8
    const int idx  = bid >> 3;           // 0..95 within XCD
    const int tokl = idx / 12;           // 0..7  (tok-local, outer)
    const int yzl  = idx % 12;           // 0..11 (yz-local, inner -> W hot)
    const int tokb = (xcd >> 1) * 8 + tokl;   // 0..31
    const int yz   = (xcd & 1) * 12 + yzl;    // 0..23
    const int z    = yz >> 3;            // 0..2
    const int yb   = yz & 7;             // 0..7

    const float* __restrict__ bias = (z == 0) ? bq : (z == 1) ? bk : bv;
    const unsigned short* __restrict__ wtz = wt + (size_t)z * C_ * C_;

    const int tok0 = tokb * 128;
    const int col0 = yb * 128;
    const int wv    = threadIdx.x >> 6;
    const int lane  = threadIdx.x & 63;
    const int l15   = lane & 15;
    const int quad  = lane >> 4;
    const int l7    = l15 & 7;
    const int wm    = wv >> 1;
    const int wn    = wv & 1;
    const int lrow8 = lane >> 3;
    const int gch   = (lane & 7) ^ lrow8;

    f32x4 acc[4][4];
#pragma unroll
    for (int i = 0; i < 4; i++)
#pragma unroll
        for (int j = 0; j < 4; j++) acc[i][j] = (f32x4){0.f, 0.f, 0.f, 0.f};

    int aoff[4][2], boff[4][2];
#pragma unroll
    for (int i = 0; i < 4; i++)
#pragma unroll
        for (int s = 0; s < 2; s++) {
            aoff[i][s] = (wm * 64 + i * 16 + l15) * 64 + (((s * 4 + quad) ^ l7) * 8);
            boff[i][s] = (wn * 64 + i * 16 + l15) * 64 + (((s * 4 + quad) ^ l7) * 8);
        }

#define STAGE_QKV(k0v, bi) do {                                               \
    _Pragma("unroll")                                                         \
    for (int s = 0; s < 8; ++s) {                                             \
        int g    = (s << 2) + wv;                                             \
        int tsel = g >> 4;                                                    \
        int r0   = (g & 15) << 3;                                             \
        const unsigned short* src = tsel ? wtz : xf;                          \
        unsigned short*       dst = tsel ? &sW[bi][0] : &sX[bi][0];           \
        int rowg = tsel ? col0 : tok0;                                        \
        gll16(src + (size_t)(rowg + r0 + lrow8) * C_ + (k0v) + gch * 8,       \
              dst + r0 * 64);                                                 \
    }                                                                         \
} while (0)

    STAGE_QKV(0, 0);

    for (int k0 = 0; k0 < C_; k0 += 64) {
        const int cur = (k0 >> 6) & 1;
        __syncthreads();                 // drains vmcnt(0): buf[cur] ready
        if (k0 + 64 < C_) STAGE_QKV(k0 + 64, cur ^ 1);

        const unsigned short* Abuf = (z < 2) ? &sX[cur][0] : &sW[cur][0];
        const unsigned short* Bbuf = (z < 2) ? &sW[cur][0] : &sX[cur][0];

        half8 af[4][2], bf_[4][2];
#pragma unroll
        for (int i = 0; i < 4; i++)
#pragma unroll
            for (int s = 0; s < 2; s++) {
                af[i][s]  = *(const half8*)&Abuf[aoff[i][s]];
                bf_[i][s] = *(const half8*)&Bbuf[boff[i][s]];
            }
#pragma unroll
        for (int s = 0; s < 2; s++)
#pragma unroll
            for (int j = 0; j < 4; j++)
#pragma unroll
                for (int i = 0; i < 4; i++)
                    acc[i][j] = __builtin_amdgcn_mfma_f32_16x16x32_f16(
                        af[i][s], bf_[j][s], acc[i][j], 0, 0, 0);
    }
#undef STAGE_QKV

    if (z == 0) {
#pragma unroll
        for (int j = 0; j < 4; j++) {
            int col = col0 + wn * 64 + j * 16 + l15;
            int h = col >> 6, d = col & 63;
            float bs = bias[col];
#pragma unroll
            for (int i = 0; i < 4; i++) {
#pragma unroll
                for (int r = 0; r < 4; r++) {
                    int tok = tok0 + wm * 64 + i * 16 + quad * 4 + r;
                    int bidx = tok >> 11, t = tok & (T_ - 1);
                    qb[((size_t)(bidx * H_ + h) * T_ + t) * DH_ + d] =
                        f2h((acc[i][j][r] + bs) * 0.18033688011112042f);
                }
            }
        }
    } else if (z == 1) {
#pragma unroll
        for (int j = 0; j < 4; j++) {
            int col = col0 + wn * 64 + j * 16 + l15;
            int h = col >> 6, d = col & 63;
            float bs = bias[col];
#pragma unroll
            for (int i = 0; i < 4; i++) {
#pragma unroll
                for (int r = 0; r < 4; r++) {
                    int tok = tok0 + wm * 64 + i * 16 + quad * 4 + r;
                    int bidx = tok >> 11, t = tok & (T_ - 1);
                    kb[((size_t)(bidx * H_ + h) * T_ + t) * DH_ + d] =
                        f2h(acc[i][j][r] + bs);
                }
            }
        }
    } else {
        float mv4[4]; int bidx4[4], t4[4];
#pragma unroll
        for (int j = 0; j < 4; j++) {
            int tok = tok0 + wn * 64 + j * 16 + l15;
            bidx4[j] = tok >> 11; t4[j] = tok & (T_ - 1);
            mv4[j] = (maskp[bidx4[j] * T_ + t4[j]] != 0) ? 1.f : 0.f;
        }
#pragma unroll
        for (int i = 0; i < 4; i++) {
#pragma unroll
            for (int r = 0; r < 4; r++) {
                int col = col0 + wm * 64 + i * 16 + quad * 4 + r;
                int h = col >> 6, d = col & 63;
                float bs = bias[col];
#pragma unroll
                for (int j = 0; j < 4; j++) {
                    vt[((size_t)(bidx4[j] * H_ + h) * DH_ + d) * T_ + t4[j]] =
                        f2h((acc[i][j][r] + bs) * mv4[j]);
                }
            }
        }
    }
}

// ---------------------------------------------------------------------------
// Attention R23: T15 software pipeline on the R18 structure. Counters showed
// the three pipes (MFMA 1330 / VALU 1330 / LDS 1340 cyc per CU-kt) are
// perfectly ADDITIVE (sum == measured 4000) — zero overlap, intra-wave serial
// chain QK->exp->pack->PV with only 2 lockstep waves/SIMD. Fix: two P states;
// per step, QK(kt+1)+softmax -> pa_next runs interleaved with PV(kt)+l(kt)
// consuming pa_cur (independent register streams, no barrier between).
// K is staged one tile deeper than V; both stay 2-deep (32KB LDS), one
// __syncthreads per kt. Accumulation order unchanged -> identical output.
// ---------------------------------------------------------------------------
__global__ __launch_bounds__(256, 2) void attn_mfma_kernel(
    const unsigned short* __restrict__ qb,  // [32][2048][64] f16 (pre-scaled)
    const unsigned short* __restrict__ kb,  // [32][2048][64] f16
    const unsigned short* __restrict__ vt,  // [32][64][2048] f16 (mask-zeroed)
    const int* __restrict__ mask,           // [2][2048]
    const unsigned short* __restrict__ mb,  // [2][2048] f16 {0,1}
    float* __restrict__ out)                // [2][2048][1024]
{
    __shared__ unsigned short Ks[2][64 * 64];
    __shared__ unsigned short Vs[2][64 * 64];

    const int bh   = blockIdx.x;            // bh-major: same head -> same XCD
    const int b    = bh >> 4;
    const int h    = bh & 15;
    const int wv   = threadIdx.x >> 6;      // 0..3
    const int lane = threadIdx.x & 63;
    const int l31  = lane & 31;
    const int hi   = lane >> 5;
    const int l7b  = l31 & 7;               // row&7 for swizzled frag reads
    const int q0w  = blockIdx.y * 128 + wv * 32;

    const unsigned short* kbh = kb + (size_t)bh * T_ * DH_;
    const unsigned short* vbh = vt + (size_t)bh * DH_ * T_;
    const unsigned short* mbb = mb + b * T_;
    const int* __restrict__ mrow = mask + b * T_;

    // Q B-frags (32x32x16): B[k=dh][n=q]: lane n=l31, k = hi*8+j per m-chunk
    half8 qf[4];
#pragma unroll
    for (int m = 0; m < 4; ++m)
        qf[m] = *(const half8*)(qb + ((size_t)bh * T_ + q0w + l31) * DH_
                                + m * 16 + hi * 8);

    f32x16 o0, o1, lacc;
#pragma unroll
    for (int r = 0; r < 16; ++r) { o0[r] = 0.f; o1[r] = 0.f; lacc[r] = 0.f; }

    const int lrow = lane >> 3;
    const int gch  = (lane & 7) ^ lrow;

// QK(tile in KRDp) -> exp2 -> packed A-frags into PA[0..3]
#define QK_BLOCK(KRDp, PA) do {                                               \
    _Pragma("unroll")                                                         \
    for (int st = 0; st < 2; ++st) {                                          \
        f32x16 sa;                                                            \
        _Pragma("unroll") for (int r = 0; r < 16; ++r) sa[r] = 0.f;           \
        _Pragma("unroll") for (int m = 0; m < 4; ++m) {                       \
            half8 kf = *(const half8*)((KRDp) + (st * 32 + l31) * 64          \
                                       + (((m * 2 + hi) ^ l7b) * 8));         \
            sa = __builtin_amdgcn_mfma_f32_32x32x16_f16(kf, qf[m], sa, 0,0,0);\
        }                                                                     \
        float p[16];                                                          \
        _Pragma("unroll") for (int r = 0; r < 16; ++r)                        \
            p[r] = __builtin_amdgcn_exp2f(sa[r]);                             \
        _Pragma("unroll") for (int kh = 0; kh < 2; ++kh) {                    \
            unsigned w0 = pk2(p[kh * 8 + 0], p[kh * 8 + 1]);                  \
            unsigned w2 = pk2(p[kh * 8 + 4], p[kh * 8 + 5]);                  \
            unsigned w1 = pk2(p[kh * 8 + 2], p[kh * 8 + 3]);                  \
            unsigned w3 = pk2(p[kh * 8 + 6], p[kh * 8 + 7]);                  \
            plswap(w0, w2);                                                   \
            plswap(w1, w3);                                                   \
            union { unsigned u[4]; half8 hh; } cv;                            \
            cv.u[0] = w0; cv.u[1] = w1; cv.u[2] = w2; cv.u[3] = w3;           \
            (PA)[st * 2 + kh] = cv.hh;                                        \
        }                                                                     \
    }                                                                         \
} while (0)

// l(KT) += P.mask ; O += P(KT) x V(tile in VRDp)
#define PV_BLOCK(KT, VRDp, PAC) do {                                          \
    half8 bmx[4];                                                             \
    _Pragma("unroll") for (int c = 0; c < 4; ++c)                             \
        bmx[c] = *(const half8*)(mbb + (KT) * 64 + c * 16 + hi * 8);          \
    _Pragma("unroll") for (int c = 0; c < 4; ++c)                             \
        lacc = __builtin_amdgcn_mfma_f32_32x32x16_f16((PAC)[c], bmx[c],       \
                                                      lacc, 0, 0, 0);         \
    _Pragma("unroll") for (int c = 0; c < 4; ++c) {                           \
        half8 v0 = *(const half8*)((VRDp) + (l31) * 64                        \
                                   + (((c * 2 + hi) ^ l7b) * 8));             \
        half8 v1 = *(const half8*)((VRDp) + (32 + l31) * 64                   \
                                   + (((c * 2 + hi) ^ l7b) * 8));             \
        o0 = __builtin_amdgcn_mfma_f32_32x32x16_f16((PAC)[c], v0, o0, 0,0,0); \
        o1 = __builtin_amdgcn_mfma_f32_32x32x16_f16((PAC)[c], v1, o1, 0,0,0); \
    }                                                                         \
} while (0)

// one pipeline step KT: stage K(KT+2)->KD, V(KT+1)->VD; QK(KT+1)->PAN from KR;
// PV(KT)+l(KT) from PAC and VR. One barrier; QK and PV streams independent.
#define ATTN_STEP(KT, KD, KR, VD, VR, PAC, PAN, DOK) do {                     \
    __syncthreads();                                                          \
    {                                                                         \
        const int nbk = ((KT) + 2) * 64, nbv = ((KT) + 1) * 64;               \
        _Pragma("unroll") for (int s = 0; s < 4; ++s) {                       \
            int j = (wv << 2) + s, rb = j & 7;                                \
            if (j < 8) {                                                      \
                if (DOK) gll16(kbh + (size_t)(nbk + rb * 8 + lrow) * DH_      \
                               + gch * 8, &(KD)[rb * 512]);                   \
            } else {                                                          \
                gll16(vbh + (size_t)(rb * 8 + lrow) * T_ + nbv + gch * 8,     \
                      &(VD)[rb * 512]);                                       \
            }                                                                 \
        }                                                                     \
    }                                                                         \
    QK_BLOCK(&(KR)[0], PAN);                                                  \
    PV_BLOCK(KT, &(VR)[0], PAC);                                              \
} while (0)

    // prologue: stage K(0)->Ks[0], V(0)->Vs[0]; K(1)->Ks[1] (all 4 waves)
#pragma unroll
    for (int s = 0; s < 4; ++s) {
        int j = (wv << 2) + s, rb = j & 7;
        if (j < 8) gll16(kbh + (size_t)(rb * 8 + lrow) * DH_ + gch * 8, &Ks[0][rb * 512]);
        else       gll16(vbh + (size_t)(rb * 8 + lrow) * T_  + gch * 8, &Vs[0][rb * 512]);
    }
#pragma unroll
    for (int s = 0; s < 2; ++s) {
        int rb = (wv << 1) + s;
        gll16(kbh + (size_t)(64 + rb * 8 + lrow) * DH_ + gch * 8, &Ks[1][rb * 512]);
    }
    __syncthreads();

    half8 paA[4], paB[4];
    QK_BLOCK(&Ks[0][0], paA);           // P(0)

    for (int kt = 0; kt < 30; kt += 2) {
        ATTN_STEP(kt,     Ks[0], Ks[1], Vs[1], Vs[0], paA, paB, true);
        ATTN_STEP(kt + 1, Ks[1], Ks[0], Vs[0], Vs[1], paB, paA, true);
    }
    ATTN_STEP(30, Ks[0], Ks[1], Vs[1], Vs[0], paA, paB, false);

    // epilogue: PV(31) + l(31) from paB, V(31) in Vs[1]
    __syncthreads();
    PV_BLOCK(31, &Vs[1][0], paB);

#undef ATTN_STEP
#undef PV_BLOCK
#undef QK_BLOCK

    // Epilogue: C row r -> q = q0w + (r&3) + 8*(r>>2) + 4*hi; l[q] = lacc[r]
    // (present in every lane). Cols: d = nt*32 + l31.
#pragma unroll
    for (int r = 0; r < 16; ++r) {
        int q = q0w + (r & 3) + 8 * (r >> 2) + 4 * hi;
        float lv = lacc[r];
        float iv = (mrow[q] != 0 && lv > 0.f) ? (1.0f / lv) : 0.f;
        float* orow = out + ((size_t)(b * T_ + q)) * C_ + h * DH_;
        orow[l31]      = o0[r] * iv;
        orow[32 + l31] = o1[r] * iv;
    }
}

// ---------------------------------------------------------------------------
extern "C" void kernel_launch(void* const* d_in, const int* in_sizes, int n_in,
                              void* d_out, int out_size, void* d_ws, size_t ws_size,
                              hipStream_t stream)
{
    (void)in_sizes; (void)n_in; (void)out_size; (void)ws_size;
    const float* x  = (const float*)d_in[0];
    const float* Wq = (const float*)d_in[1];
    const float* bq = (const float*)d_in[2];
    const float* Wk = (const float*)d_in[3];
    const float* bk = (const float*)d_in[4];
    const float* Wv = (const float*)d_in[5];
    const float* bv = (const float*)d_in[6];
    const int* mask = (const int*)d_in[7];
    float* out = (float*)d_out;

    const size_t NX = (size_t)B_ * T_ * C_;          // 4 Mi elements
    unsigned short* xf = (unsigned short*)d_ws;       // 8 MB fp16 x
    unsigned short* wt = xf + NX;                     // 6 MB fp16 W^T x3
    unsigned short* qb = wt + (size_t)3 * C_ * C_;    // 8 MB (pre-scaled q)
    unsigned short* kb = qb + NX;                     // 8 MB
    unsigned short* vt = kb + NX;                     // 8 MB
    unsigned short* mb = vt + NX;                     // 8 KB

    prep_kernel<<<5120, 256, 0, stream>>>(x, xf, mask, mb, Wq, Wk, Wv, wt);
    qkv_mfma_kernel<<<768, 256, 0, stream>>>(
        xf, wt, bq, bk, bv, mask, qb, kb, vt);
    attn_mfma_kernel<<<dim3(32, 16), 256, 0, stream>>>(qb, kb, vt, mask, mb, out);
}